// Round 14
// baseline (216.131 us; speedup 1.0000x reference)
//
#include <hip/hip_runtime.h>
#include <hip/hip_bf16.h>

typedef short short8 __attribute__((ext_vector_type(8)));
typedef float f32x4 __attribute__((ext_vector_type(4)));
typedef float f32x16 __attribute__((ext_vector_type(16)));
typedef unsigned int uint4v __attribute__((ext_vector_type(4)));

#define MFMA16(a, b, c) __builtin_amdgcn_mfma_f32_16x16x32_bf16(a, b, c, 0, 0, 0)
#define MFMA32(a, b, c) __builtin_amdgcn_mfma_f32_32x32x16_bf16(a, b, c, 0, 0, 0)

typedef __attribute__((address_space(1))) const unsigned int gas_u32;
typedef __attribute__((address_space(3))) unsigned int las_u32;

__device__ inline void gll16(const void* g, void* l) {
    __builtin_amdgcn_global_load_lds((gas_u32*)g, (las_u32*)l, 16, 0, 0);
}

__device__ inline unsigned short f2bf(float f) {
    unsigned u = __builtin_bit_cast(unsigned, f);
    u += 0x7fff + ((u >> 16) & 1);   // RNE (inputs finite)
    return (unsigned short)(u >> 16);
}

__device__ inline unsigned pk_perm(float a, float b, unsigned sel) {
    unsigned r;
    asm("v_perm_b32 %0, %1, %2, %3"
        : "=v"(r)
        : "v"(__builtin_bit_cast(unsigned, b)), "v"(__builtin_bit_cast(unsigned, a)), "s"(sel));
    return r;
}

__device__ inline float exp2_fast(float x) {
#if __has_builtin(__builtin_amdgcn_exp2f)
    return __builtin_amdgcn_exp2f(x);
#else
    float r; asm("v_exp_f32 %0, %1" : "=v"(r) : "v"(x)); return r;
#endif
}

__device__ inline void pl32_swap(unsigned &a, unsigned &b) {
    asm volatile("v_permlane32_swap_b32 %0, %1" : "+v"(a), "+v"(b));
}

// ------------------------------------------------------------------
__global__ void pe_cast3(const float* __restrict__ q, const float* __restrict__ k,
                         const float* __restrict__ v, const float* __restrict__ pe,
                         unsigned short* __restrict__ oq, unsigned short* __restrict__ ok,
                         unsigned short* __restrict__ ov) {
    const float* x = (blockIdx.y == 0) ? q : (blockIdx.y == 1) ? k : v;
    unsigned short* o = (blockIdx.y == 0) ? oq : (blockIdx.y == 1) ? ok : ov;
    int i = blockIdx.x * 256 + threadIdx.x;
    long e = (long)i * 4;
    int b = (int)(e >> 21);
    int d = (int)(e & 1023);
    float4 xv = reinterpret_cast<const float4*>(x)[i];
    float4 pv = *reinterpret_cast<const float4*>(pe + b * 1024 + d);
    ushort4 r;
    r.x = f2bf(xv.x + pv.x); r.y = f2bf(xv.y + pv.y);
    r.z = f2bf(xv.z + pv.z); r.w = f2bf(xv.w + pv.w);
    reinterpret_cast<ushort4*>(o)[i] = r;
}

__global__ void wcast4(const float* __restrict__ w0, const float* __restrict__ w1,
                       const float* __restrict__ w2, const float* __restrict__ w3,
                       unsigned short* __restrict__ o0) {
    const float* w = (blockIdx.y == 0) ? w0 : (blockIdx.y == 1) ? w1
                   : (blockIdx.y == 2) ? w2 : w3;
    unsigned short* o = o0 + (size_t)blockIdx.y * 1024 * 1024;
    int i = blockIdx.x * 256 + threadIdx.x;
    float4 xv = reinterpret_cast<const float4*>(w)[i];
    ushort4 r;
    r.x = f2bf(xv.x); r.y = f2bf(xv.y); r.z = f2bf(xv.z); r.w = f2bf(xv.w);
    reinterpret_cast<ushort4*>(o)[i] = r;
}

// ------------------------------------------------------------------
// gemm8: m201-style 8-phase 256x256 GEMM.  BK=64, 512 thr (8 waves 2x4),
// wave tile 128x64, 16x16x32 MFMA, double-buffered 128KB LDS.
// Per K-tile: 4 quadrant-phases {ds-read frags; stage 2 units; [vmcnt@q2/q4];
// s_barrier; MFMA x16 @setprio; s_barrier}.  Counted vmcnt, never 0 mid-loop.
// Staging units (1 gll16/thread each): uA0..3 / uB0..3 = 64-row groups.
// Consumption: q1 needs uB*,uA0,uA2; q3 needs uA1,uA3.
// Issue for t+1: q1:uB0,uB1  q2:uB2,uB3(+vmcnt4)  q3:uA0,uA2  q4:uA1,uA3(+vmcnt2).
// MODE 3: Q/K/V via blockIdx.z (z<2 head-split bf16; z=2 V^T ushort4-packed).
// MODE 1: f32 [m][n].
template <int MODE>
__global__ __launch_bounds__(512, 2) void gemm8(const unsigned short* __restrict__ A0,
                                                const unsigned short* __restrict__ W0,
                                                const float* __restrict__ bq,
                                                const float* __restrict__ bk,
                                                const float* __restrict__ bv,
                                                void* __restrict__ oq,
                                                void* __restrict__ ok,
                                                void* __restrict__ ov,
                                                float qscale) {
    const int NT = 16;                        // K=1024 / BK=64
    __shared__ __align__(16) unsigned short lsA[2][256 * 64];
    __shared__ __align__(16) unsigned short lsB[2][256 * 64];

    int z = (MODE == 3) ? blockIdx.z : 0;
    const unsigned short* A = A0 + (size_t)z * 8192 * 1024;
    const unsigned short* W = W0 + (size_t)z * 1024 * 1024;
    const float* bias = (MODE == 3) ? ((z == 0) ? bq : (z == 1) ? bk : bv) : bq;
    float scale = (MODE == 3 && z == 0) ? qscale : 1.0f;

    int tid = threadIdx.x, wave = tid >> 6, lane = tid & 63;
    int lg = lane >> 4, l15 = lane & 15;
    int wr = wave >> 2, wc = wave & 3;        // 2 x 4 wave grid
    int brow = blockIdx.x * 256;
    int bcol = blockIdx.y * 256;

    // staging source (r11/r12-verified: 0 conflicts): unit q stages rows
    // q*64+srow; source col pre-swizzled so linear LDS dest + XOR read match.
    int srow = tid >> 3;
    int scol = ((tid ^ srow) & 7) * 8;
    const unsigned short* pA = A + (long)(brow + srow) * 1024 + scol;
    const unsigned short* pB = W + (long)(bcol + srow) * 1024 + scol;

    f32x4 acc[8][4];
#pragma unroll
    for (int m = 0; m < 8; ++m)
#pragma unroll
        for (int n = 0; n < 4; ++n) acc[m][n] = f32x4{0.f, 0.f, 0.f, 0.f};

#define SA(t, bi, q) gll16(pA + (t) * 64 + (q) * 65536,                     \
                           (char*)lsA[bi] + ((q) * 512 + wave * 64) * 16)
#define SB(t, bi, q) gll16(pB + (t) * 64 + (q) * 65536,                     \
                           (char*)lsB[bi] + ((q) * 512 + wave * 64) * 16)

    // prologue: tile 0 in consumption order; allow uA1,uA3 outstanding
    SB(0, 0, 0); SB(0, 0, 1); SB(0, 0, 2); SB(0, 0, 3);
    SA(0, 0, 0); SA(0, 0, 2); SA(0, 0, 1); SA(0, 0, 3);
    asm volatile("s_waitcnt vmcnt(2)" ::: "memory");
    __builtin_amdgcn_s_barrier();

    int swz_ = (l15 & 7) << 4;
    for (int t = 0; t < NT; ++t) {
        int cb = t & 1, nb = cb ^ 1;
        const char* KA = (const char*)lsA[cb];
        const char* KB = (const char*)lsB[cb];
        short8 af0[4][2], af1[4][2], bf0[2][2], bf1[2][2];
        const bool st = (t < NT - 1);

        // ===== q1: (m0-3, n0-1) =====
#pragma unroll
        for (int m = 0; m < 4; ++m)
#pragma unroll
            for (int kk = 0; kk < 2; ++kk)
                af0[m][kk] = *(const short8*)(KA + (wr * 128 + m * 16 + l15) * 128 +
                                              (((kk * 4 + lg) << 4) ^ swz_));
#pragma unroll
        for (int n = 0; n < 2; ++n)
#pragma unroll
            for (int kk = 0; kk < 2; ++kk)
                bf0[n][kk] = *(const short8*)(KB + (wc * 64 + n * 16 + l15) * 128 +
                                              (((kk * 4 + lg) << 4) ^ swz_));
        if (st) { SB(t + 1, nb, 0); SB(t + 1, nb, 1); }
        __builtin_amdgcn_s_barrier();
        asm volatile("s_waitcnt lgkmcnt(0)" ::: "memory");
        __builtin_amdgcn_s_setprio(1);
#pragma unroll
        for (int m = 0; m < 4; ++m)
#pragma unroll
            for (int n = 0; n < 2; ++n)
#pragma unroll
                for (int kk = 0; kk < 2; ++kk)
                    acc[m][n] = MFMA16(af0[m][kk], bf0[n][kk], acc[m][n]);
        __builtin_amdgcn_s_setprio(0);
        __builtin_amdgcn_s_barrier();

        // ===== q2: (m0-3, n2-3) =====
#pragma unroll
        for (int n = 0; n < 2; ++n)
#pragma unroll
            for (int kk = 0; kk < 2; ++kk)
                bf1[n][kk] = *(const short8*)(KB + (wc * 64 + (n + 2) * 16 + l15) * 128 +
                                              (((kk * 4 + lg) << 4) ^ swz_));
        if (st) { SB(t + 1, nb, 2); SB(t + 1, nb, 3); }
        if (st) { asm volatile("s_waitcnt vmcnt(4)" ::: "memory"); }    // t's uA1,uA3 done
        else    { asm volatile("s_waitcnt vmcnt(0)" ::: "memory"); }
        __builtin_amdgcn_s_barrier();
        asm volatile("s_waitcnt lgkmcnt(0)" ::: "memory");
        __builtin_amdgcn_s_setprio(1);
#pragma unroll
        for (int m = 0; m < 4; ++m)
#pragma unroll
            for (int n = 0; n < 2; ++n)
#pragma unroll
                for (int kk = 0; kk < 2; ++kk)
                    acc[m][n + 2] = MFMA16(af0[m][kk], bf1[n][kk], acc[m][n + 2]);
        __builtin_amdgcn_s_setprio(0);
        __builtin_amdgcn_s_barrier();

        // ===== q3: (m4-7, n0-1) =====
#pragma unroll
        for (int m = 0; m < 4; ++m)
#pragma unroll
            for (int kk = 0; kk < 2; ++kk)
                af1[m][kk] = *(const short8*)(KA + (wr * 128 + (m + 4) * 16 + l15) * 128 +
                                              (((kk * 4 + lg) << 4) ^ swz_));
        if (st) { SA(t + 1, nb, 0); SA(t + 1, nb, 2); }
        __builtin_amdgcn_s_barrier();
        asm volatile("s_waitcnt lgkmcnt(0)" ::: "memory");
        __builtin_amdgcn_s_setprio(1);
#pragma unroll
        for (int m = 0; m < 4; ++m)
#pragma unroll
            for (int n = 0; n < 2; ++n)
#pragma unroll
                for (int kk = 0; kk < 2; ++kk)
                    acc[m + 4][n] = MFMA16(af1[m][kk], bf0[n][kk], acc[m + 4][n]);
        __builtin_amdgcn_s_setprio(0);
        __builtin_amdgcn_s_barrier();

        // ===== q4: (m4-7, n2-3) =====
        if (st) {
            SA(t + 1, nb, 1); SA(t + 1, nb, 3);
            asm volatile("s_waitcnt vmcnt(2)" ::: "memory");   // t+1's uB*,uA0,uA2 done
        }
        __builtin_amdgcn_s_barrier();
        __builtin_amdgcn_s_setprio(1);
#pragma unroll
        for (int m = 0; m < 4; ++m)
#pragma unroll
            for (int n = 0; n < 2; ++n)
#pragma unroll
                for (int kk = 0; kk < 2; ++kk)
                    acc[m + 4][n + 2] = MFMA16(af1[m][kk], bf1[n][kk], acc[m + 4][n + 2]);
        __builtin_amdgcn_s_setprio(0);
        __builtin_amdgcn_s_barrier();
    }
#undef SA
#undef SB

    // ---- epilogue ----
    void* out = (MODE == 3) ? ((z == 0) ? oq : (z == 1) ? ok : ov) : oq;
#pragma unroll
    for (int m = 0; m < 8; ++m)
#pragma unroll
        for (int n = 0; n < 4; ++n) {
            int col = bcol + wc * 64 + n * 16 + l15;
            float bv_ = bias[col];
            int row0 = brow + wr * 128 + m * 16 + lg * 4;
            if (MODE == 3 && z == 2) {
                int b = row0 >> 11, s0 = row0 & 2047;
                ushort4 pk;
                pk.x = f2bf(acc[m][n][0] + bv_);
                pk.y = f2bf(acc[m][n][1] + bv_);
                pk.z = f2bf(acc[m][n][2] + bv_);
                pk.w = f2bf(acc[m][n][3] + bv_);
                *(ushort4*)((unsigned short*)out + ((long)(b * 1024 + col)) * 2048 + s0) = pk;
            } else {
#pragma unroll
                for (int r = 0; r < 4; ++r) {
                    int row = row0 + r;
                    float v = (acc[m][n][r] + bv_) * scale;
                    if (MODE == 1) {
                        ((float*)out)[(long)row * 1024 + col] = v;
                    } else {
                        int b = row >> 11, s = row & 2047, h = col >> 6, d = col & 63;
                        ((unsigned short*)out)[(((long)(b * 16 + h) * 2048 + s) * 64 + d)] = f2bf(v);
                    }
                }
            }
        }
}

// ------------------------------------------------------------------
// Flash attention (round-10 version, unchanged).
__global__ __launch_bounds__(256, 2) void attn_kernel(const unsigned short* __restrict__ Qh,
                                                      const unsigned short* __restrict__ Kh,
                                                      const unsigned short* __restrict__ Vt,
                                                      unsigned short* __restrict__ Om) {
    const int S = 2048;
    const int NT = S / 64;
    int flat = blockIdx.x;
    int nf_ = (flat & 7) * 64 + (flat >> 3);
    int qt = nf_ & 7;
    int bh = nf_ >> 3;
    int b = bh >> 4, h = bh & 15;

    int tid = threadIdx.x, wave = tid >> 6, lane = tid & 63;
    int l31 = lane & 31, hi = lane >> 5;

    __shared__ __align__(16) unsigned short Kl[3][4096];
    __shared__ __align__(16) unsigned short Vtl[3][4096];

    const unsigned short* Qb = Qh + (long)bh * S * 64;
    const unsigned short* Kb = Kh + (long)bh * S * 64;
    const unsigned short* Vb = Vt + (long)bh * 64 * S;

    int colS = ((((tid & 7) * 16) ^ (((tid >> 3) & 7) << 4)) >> 1);
    const unsigned short* srcK = Kb + (tid >> 3) * 64 + colS;
    const unsigned short* srcV = Vb + (tid >> 3) * 2048 + colS;

    short8 aq[2][4];
    {
        const unsigned short* qrow = Qb + (long)(qt * 256 + wave * 64 + l31) * 64 + hi * 8;
#pragma unroll
        for (int qf = 0; qf < 2; ++qf)
#pragma unroll
            for (int s = 0; s < 4; ++s)
                aq[qf][s] = *(const short8*)(qrow + qf * 32 * 64 + s * 16);
    }

    f32x16 oacc[2][2], lacc[2], z16;
#pragma unroll
    for (int r = 0; r < 16; ++r) {
        oacc[0][0][r] = 0.f; oacc[0][1][r] = 0.f;
        oacc[1][0][r] = 0.f; oacc[1][1][r] = 0.f;
        lacc[0][r] = 0.f; lacc[1][r] = 0.f;
        z16[r] = 0.f;
    }

    const short8 ones8 = {0x3F80, 0x3F80, 0x3F80, 0x3F80, 0x3F80, 0x3F80, 0x3F80, 0x3F80};
    const unsigned SEL = 0x07060302u;

    int rb0 = l31 * 128;
    int swz = (l31 & 7) << 4;

#define STAGE(kt, bi) do {                                              \
        const unsigned short* sk = srcK + (kt) * 4096;                  \
        gll16(sk,         (char*)Kl[bi] + wave * 1024);                 \
        gll16(sk + 2048,  (char*)Kl[bi] + 4096 + wave * 1024);          \
        const unsigned short* sv = srcV + (kt) * 64;                    \
        gll16(sv,         (char*)Vtl[bi] + wave * 1024);                \
        gll16(sv + 65536, (char*)Vtl[bi] + 4096 + wave * 1024);         \
    } while (0)

    STAGE(0, 0);
    STAGE(1, 1);

    int bi = 0, sb = 2;
    for (int kt = 0; kt < NT; ++kt) {
        if (kt == NT - 1) { asm volatile("s_waitcnt vmcnt(0)" ::: "memory"); }
        else              { asm volatile("s_waitcnt vmcnt(4)" ::: "memory"); }
        __builtin_amdgcn_s_barrier();
        if (kt < NT - 2) STAGE(kt + 2, sb);

        const char* KlC = (const char*)Kl[bi];
        const char* VlC = (const char*)Vtl[bi];

        f32x16 sacc[2][2];
        __builtin_amdgcn_s_setprio(1);
#pragma unroll
        for (int blk = 0; blk < 2; ++blk) {
            short8 kf0 = *(const short8*)(KlC + blk * 4096 + rb0 + ((16 * hi) ^ swz));
            sacc[0][blk] = MFMA32(kf0, aq[0][0], z16);
            sacc[1][blk] = MFMA32(kf0, aq[1][0], z16);
#pragma unroll
            for (int s = 1; s < 4; ++s) {
                short8 kf = *(const short8*)(KlC + blk * 4096 + rb0 + ((32 * s + 16 * hi) ^ swz));
                sacc[0][blk] = MFMA32(kf, aq[0][s], sacc[0][blk]);
                sacc[1][blk] = MFMA32(kf, aq[1][s], sacc[1][blk]);
            }
        }
        __builtin_amdgcn_s_setprio(0);

#pragma unroll
        for (int qf = 0; qf < 2; ++qf)
#pragma unroll
            for (int blk = 0; blk < 2; ++blk)
#pragma unroll
                for (int r = 0; r < 16; ++r) sacc[qf][blk][r] = exp2_fast(sacc[qf][blk][r]);

#pragma unroll
        for (int s = 0; s < 4; ++s) {
            const int blk = s >> 1, base = (s & 1) * 8;
            short8 pa[2];
#pragma unroll
            for (int qf = 0; qf < 2; ++qf) {
                unsigned q0 = pk_perm(sacc[qf][blk][base + 0], sacc[qf][blk][base + 1], SEL);
                unsigned q1 = pk_perm(sacc[qf][blk][base + 2], sacc[qf][blk][base + 3], SEL);
                unsigned q2 = pk_perm(sacc[qf][blk][base + 4], sacc[qf][blk][base + 5], SEL);
                unsigned q3 = pk_perm(sacc[qf][blk][base + 6], sacc[qf][blk][base + 7], SEL);
                pl32_swap(q0, q2);
                pl32_swap(q1, q3);
                uint4v pw; pw[0] = q0; pw[1] = q1; pw[2] = q2; pw[3] = q3;
                pa[qf] = __builtin_bit_cast(short8, pw);
            }
            __builtin_amdgcn_s_setprio(1);
#pragma unroll
            for (int dblk = 0; dblk < 2; ++dblk) {
                short8 vf = *(const short8*)(VlC + dblk * 4096 + rb0 + ((32 * s + 16 * hi) ^ swz));
                oacc[0][dblk] = MFMA32(pa[0], vf, oacc[0][dblk]);
                oacc[1][dblk] = MFMA32(pa[1], vf, oacc[1][dblk]);
            }
            lacc[0] = MFMA32(pa[0], ones8, lacc[0]);
            lacc[1] = MFMA32(pa[1], ones8, lacc[1]);
            __builtin_amdgcn_s_setprio(0);
        }
        bi = (bi == 2) ? 0 : bi + 1;
        sb = (sb == 2) ? 0 : sb + 1;
    }
#undef STAGE

#pragma unroll
    for (int qf = 0; qf < 2; ++qf) {
        float inv[16];
#pragma unroll
        for (int r = 0; r < 16; ++r) inv[r] = 1.0f / lacc[qf][r];
        int qrow0 = qt * 256 + wave * 64 + qf * 32 + 4 * hi;
#pragma unroll
        for (int dblk = 0; dblk < 2; ++dblk)
#pragma unroll
            for (int r = 0; r < 16; ++r) {
                int qrow = qrow0 + (r & 3) + 8 * (r >> 2);
                int d = h * 64 + dblk * 32 + l31;
                float v = oacc[qf][dblk][r] * inv[r];
                Om[((long)b * 2048 + qrow) * 1024 + d] = f2bf(v);
            }
    }
}

// ------------------------------------------------------------------
extern "C" void kernel_launch(void* const* d_in, const int* in_sizes, int n_in,
                              void* d_out, int out_size, void* d_ws, size_t ws_size,
                              hipStream_t stream) {
    const float* v_in = (const float*)d_in[0];
    const float* k_in = (const float*)d_in[1];
    const float* q_in = (const float*)d_in[2];
    const float* wq_w = (const float*)d_in[3];
    const float* wq_b = (const float*)d_in[4];
    const float* wk_w = (const float*)d_in[5];
    const float* wk_b = (const float*)d_in[6];
    const float* wv_w = (const float*)d_in[7];
    const float* wv_b = (const float*)d_in[8];
    const float* wd_w = (const float*)d_in[9];
    const float* wd_b = (const float*)d_in[10];
    const float* pe   = (const float*)d_in[11];

    const long SZ = 8192L * 1024 * 2;
    char* ws = (char*)d_ws;
    unsigned short* xq = (unsigned short*)(ws + 0);          // xq,xk,xv contiguous
    unsigned short* xk = (unsigned short*)(ws + SZ);
    unsigned short* xv = (unsigned short*)(ws + 2 * SZ);
    unsigned short* qh = (unsigned short*)(ws + 3 * SZ);
    unsigned short* kh = (unsigned short*)(ws + 4 * SZ);
    unsigned short* vt = (unsigned short*)(ws + 5 * SZ);
    unsigned short* wqb16 = (unsigned short*)(ws + 6 * SZ);  // wq,wk,wv,wd contiguous

    pe_cast3<<<dim3(8192, 3), 256, 0, stream>>>(q_in, k_in, v_in, pe, xq, xk, xv);
    wcast4<<<dim3(1024, 4), 256, 0, stream>>>(wq_w, wk_w, wv_w, wd_w, wqb16);

    const float QSCALE = 0.125f * 1.44269504088896f;   // fold 1/sqrt(64) * log2(e)
    // Q/K/V projections: 256x256 tiles, 8-phase schedule, 384 blocks
    gemm8<3><<<dim3(32, 4, 3), 512, 0, stream>>>(
        xq, wqb16, wq_b, wk_b, wv_b, qh, kh, vt, QSCALE);

    unsigned short* om = xq;
    attn_kernel<<<512, 256, 0, stream>>>(qh, kh, vt, om);

    // dense: 256x256 tiles, 128 blocks
    gemm8<1><<<dim3(32, 4, 1), 512, 0, stream>>>(
        om, wqb16 + 3L * 1024 * 1024, wd_b, nullptr, nullptr, d_out, nullptr, nullptr, 1.0f);
}

// Round 15
// 205.507 us; speedup vs baseline: 1.0517x; 1.0517x over previous
//
#include <hip/hip_runtime.h>
#include <hip/hip_bf16.h>

typedef short short8 __attribute__((ext_vector_type(8)));
typedef float f32x4 __attribute__((ext_vector_type(4)));
typedef float f32x16 __attribute__((ext_vector_type(16)));
typedef unsigned int uint4v __attribute__((ext_vector_type(4)));

#define MFMA16(a, b, c) __builtin_amdgcn_mfma_f32_16x16x32_bf16(a, b, c, 0, 0, 0)
#define MFMA32(a, b, c) __builtin_amdgcn_mfma_f32_32x32x16_bf16(a, b, c, 0, 0, 0)

typedef __attribute__((address_space(1))) const unsigned int gas_u32;
typedef __attribute__((address_space(3))) unsigned int las_u32;

__device__ inline void gll16(const void* g, void* l) {
    __builtin_amdgcn_global_load_lds((gas_u32*)g, (las_u32*)l, 16, 0, 0);
}

__device__ inline unsigned short f2bf(float f) {
    unsigned u = __builtin_bit_cast(unsigned, f);
    u += 0x7fff + ((u >> 16) & 1);   // RNE (inputs finite)
    return (unsigned short)(u >> 16);
}

__device__ inline unsigned pk_perm(float a, float b, unsigned sel) {
    unsigned r;
    asm("v_perm_b32 %0, %1, %2, %3"
        : "=v"(r)
        : "v"(__builtin_bit_cast(unsigned, b)), "v"(__builtin_bit_cast(unsigned, a)), "s"(sel));
    return r;
}

__device__ inline float exp2_fast(float x) {
#if __has_builtin(__builtin_amdgcn_exp2f)
    return __builtin_amdgcn_exp2f(x);
#else
    float r; asm("v_exp_f32 %0, %1" : "=v"(r) : "v"(x)); return r;
#endif
}

__device__ inline void pl32_swap(unsigned &a, unsigned &b) {
    asm volatile("v_permlane32_swap_b32 %0, %1" : "+v"(a), "+v"(b));
}

// ------------------------------------------------------------------
__global__ void pe_cast3(const float* __restrict__ q, const float* __restrict__ k,
                         const float* __restrict__ v, const float* __restrict__ pe,
                         unsigned short* __restrict__ oq, unsigned short* __restrict__ ok,
                         unsigned short* __restrict__ ov) {
    const float* x = (blockIdx.y == 0) ? q : (blockIdx.y == 1) ? k : v;
    unsigned short* o = (blockIdx.y == 0) ? oq : (blockIdx.y == 1) ? ok : ov;
    int i = blockIdx.x * 256 + threadIdx.x;
    long e = (long)i * 4;
    int b = (int)(e >> 21);
    int d = (int)(e & 1023);
    float4 xv = reinterpret_cast<const float4*>(x)[i];
    float4 pv = *reinterpret_cast<const float4*>(pe + b * 1024 + d);
    ushort4 r;
    r.x = f2bf(xv.x + pv.x); r.y = f2bf(xv.y + pv.y);
    r.z = f2bf(xv.z + pv.z); r.w = f2bf(xv.w + pv.w);
    reinterpret_cast<ushort4*>(o)[i] = r;
}

__global__ void wcast4(const float* __restrict__ w0, const float* __restrict__ w1,
                       const float* __restrict__ w2, const float* __restrict__ w3,
                       unsigned short* __restrict__ o0) {
    const float* w = (blockIdx.y == 0) ? w0 : (blockIdx.y == 1) ? w1
                   : (blockIdx.y == 2) ? w2 : w3;
    unsigned short* o = o0 + (size_t)blockIdx.y * 1024 * 1024;
    int i = blockIdx.x * 256 + threadIdx.x;
    float4 xv = reinterpret_cast<const float4*>(w)[i];
    ushort4 r;
    r.x = f2bf(xv.x); r.y = f2bf(xv.y); r.z = f2bf(xv.z); r.w = f2bf(xv.w);
    reinterpret_cast<ushort4*>(o)[i] = r;
}

// ------------------------------------------------------------------
// gemm8: m201-style 8-phase 256x256 GEMM (r14, verified).  Q/K/V only.
__global__ __launch_bounds__(512, 2) void gemm8(const unsigned short* __restrict__ A0,
                                                const unsigned short* __restrict__ W0,
                                                const float* __restrict__ bq,
                                                const float* __restrict__ bk,
                                                const float* __restrict__ bv,
                                                void* __restrict__ oq,
                                                void* __restrict__ ok,
                                                void* __restrict__ ov,
                                                float qscale) {
    const int NT = 16;                        // K=1024 / BK=64
    __shared__ __align__(16) unsigned short lsA[2][256 * 64];
    __shared__ __align__(16) unsigned short lsB[2][256 * 64];

    int z = blockIdx.z;
    const unsigned short* A = A0 + (size_t)z * 8192 * 1024;
    const unsigned short* W = W0 + (size_t)z * 1024 * 1024;
    const float* bias = (z == 0) ? bq : (z == 1) ? bk : bv;
    float scale = (z == 0) ? qscale : 1.0f;

    int tid = threadIdx.x, wave = tid >> 6, lane = tid & 63;
    int lg = lane >> 4, l15 = lane & 15;
    int wr = wave >> 2, wc = wave & 3;        // 2 x 4 wave grid
    int brow = blockIdx.x * 256;
    int bcol = blockIdx.y * 256;

    int srow = tid >> 3;
    int scol = ((tid ^ srow) & 7) * 8;
    const unsigned short* pA = A + (long)(brow + srow) * 1024 + scol;
    const unsigned short* pB = W + (long)(bcol + srow) * 1024 + scol;

    f32x4 acc[8][4];
#pragma unroll
    for (int m = 0; m < 8; ++m)
#pragma unroll
        for (int n = 0; n < 4; ++n) acc[m][n] = f32x4{0.f, 0.f, 0.f, 0.f};

#define SA(t, bi, q) gll16(pA + (t) * 64 + (q) * 65536,                     \
                           (char*)lsA[bi] + ((q) * 512 + wave * 64) * 16)
#define SB(t, bi, q) gll16(pB + (t) * 64 + (q) * 65536,                     \
                           (char*)lsB[bi] + ((q) * 512 + wave * 64) * 16)

    SB(0, 0, 0); SB(0, 0, 1); SB(0, 0, 2); SB(0, 0, 3);
    SA(0, 0, 0); SA(0, 0, 2); SA(0, 0, 1); SA(0, 0, 3);
    asm volatile("s_waitcnt vmcnt(2)" ::: "memory");
    __builtin_amdgcn_s_barrier();

    int swz_ = (l15 & 7) << 4;
    for (int t = 0; t < NT; ++t) {
        int cb = t & 1, nb = cb ^ 1;
        const char* KA = (const char*)lsA[cb];
        const char* KB = (const char*)lsB[cb];
        short8 af0[4][2], af1[4][2], bf0[2][2], bf1[2][2];
        const bool st = (t < NT - 1);

        // ===== q1: (m0-3, n0-1) =====
#pragma unroll
        for (int m = 0; m < 4; ++m)
#pragma unroll
            for (int kk = 0; kk < 2; ++kk)
                af0[m][kk] = *(const short8*)(KA + (wr * 128 + m * 16 + l15) * 128 +
                                              (((kk * 4 + lg) << 4) ^ swz_));
#pragma unroll
        for (int n = 0; n < 2; ++n)
#pragma unroll
            for (int kk = 0; kk < 2; ++kk)
                bf0[n][kk] = *(const short8*)(KB + (wc * 64 + n * 16 + l15) * 128 +
                                              (((kk * 4 + lg) << 4) ^ swz_));
        if (st) { SB(t + 1, nb, 0); SB(t + 1, nb, 1); }
        __builtin_amdgcn_s_barrier();
        asm volatile("s_waitcnt lgkmcnt(0)" ::: "memory");
        __builtin_amdgcn_s_setprio(1);
#pragma unroll
        for (int m = 0; m < 4; ++m)
#pragma unroll
            for (int n = 0; n < 2; ++n)
#pragma unroll
                for (int kk = 0; kk < 2; ++kk)
                    acc[m][n] = MFMA16(af0[m][kk], bf0[n][kk], acc[m][n]);
        __builtin_amdgcn_s_setprio(0);
        __builtin_amdgcn_s_barrier();

        // ===== q2: (m0-3, n2-3) =====
#pragma unroll
        for (int n = 0; n < 2; ++n)
#pragma unroll
            for (int kk = 0; kk < 2; ++kk)
                bf1[n][kk] = *(const short8*)(KB + (wc * 64 + (n + 2) * 16 + l15) * 128 +
                                              (((kk * 4 + lg) << 4) ^ swz_));
        if (st) { SB(t + 1, nb, 2); SB(t + 1, nb, 3); }
        if (st) { asm volatile("s_waitcnt vmcnt(4)" ::: "memory"); }
        else    { asm volatile("s_waitcnt vmcnt(0)" ::: "memory"); }
        __builtin_amdgcn_s_barrier();
        asm volatile("s_waitcnt lgkmcnt(0)" ::: "memory");
        __builtin_amdgcn_s_setprio(1);
#pragma unroll
        for (int m = 0; m < 4; ++m)
#pragma unroll
            for (int n = 0; n < 2; ++n)
#pragma unroll
                for (int kk = 0; kk < 2; ++kk)
                    acc[m][n + 2] = MFMA16(af0[m][kk], bf1[n][kk], acc[m][n + 2]);
        __builtin_amdgcn_s_setprio(0);
        __builtin_amdgcn_s_barrier();

        // ===== q3: (m4-7, n0-1) =====
#pragma unroll
        for (int m = 0; m < 4; ++m)
#pragma unroll
            for (int kk = 0; kk < 2; ++kk)
                af1[m][kk] = *(const short8*)(KA + (wr * 128 + (m + 4) * 16 + l15) * 128 +
                                              (((kk * 4 + lg) << 4) ^ swz_));
        if (st) { SA(t + 1, nb, 0); SA(t + 1, nb, 2); }
        __builtin_amdgcn_s_barrier();
        asm volatile("s_waitcnt lgkmcnt(0)" ::: "memory");
        __builtin_amdgcn_s_setprio(1);
#pragma unroll
        for (int m = 0; m < 4; ++m)
#pragma unroll
            for (int n = 0; n < 2; ++n)
#pragma unroll
                for (int kk = 0; kk < 2; ++kk)
                    acc[m + 4][n] = MFMA16(af1[m][kk], bf0[n][kk], acc[m + 4][n]);
        __builtin_amdgcn_s_setprio(0);
        __builtin_amdgcn_s_barrier();

        // ===== q4: (m4-7, n2-3) =====
        if (st) {
            SA(t + 1, nb, 1); SA(t + 1, nb, 3);
            asm volatile("s_waitcnt vmcnt(2)" ::: "memory");
        }
        __builtin_amdgcn_s_barrier();
        __builtin_amdgcn_s_setprio(1);
#pragma unroll
        for (int m = 0; m < 4; ++m)
#pragma unroll
            for (int n = 0; n < 2; ++n)
#pragma unroll
                for (int kk = 0; kk < 2; ++kk)
                    acc[m + 4][n + 2] = MFMA16(af1[m][kk], bf1[n][kk], acc[m + 4][n + 2]);
        __builtin_amdgcn_s_setprio(0);
        __builtin_amdgcn_s_barrier();
    }
#undef SA
#undef SB

    void* out = (z == 0) ? oq : (z == 1) ? ok : ov;
#pragma unroll
    for (int m = 0; m < 8; ++m)
#pragma unroll
        for (int n = 0; n < 4; ++n) {
            int col = bcol + wc * 64 + n * 16 + l15;
            float bv_ = bias[col];
            int row0 = brow + wr * 128 + m * 16 + lg * 4;
            if (z == 2) {
                int b = row0 >> 11, s0 = row0 & 2047;
                ushort4 pk;
                pk.x = f2bf(acc[m][n][0] + bv_);
                pk.y = f2bf(acc[m][n][1] + bv_);
                pk.z = f2bf(acc[m][n][2] + bv_);
                pk.w = f2bf(acc[m][n][3] + bv_);
                *(ushort4*)((unsigned short*)out + ((long)(b * 1024 + col)) * 2048 + s0) = pk;
            } else {
#pragma unroll
                for (int r = 0; r < 4; ++r) {
                    int row = row0 + r;
                    float v = (acc[m][n][r] + bv_) * scale;
                    int b = row >> 11, s = row & 2047, h = col >> 6, d = col & 63;
                    ((unsigned short*)out)[(((long)(b * 16 + h) * 2048 + s) * 64 + d)] = f2bf(v);
                }
            }
        }
}

// ------------------------------------------------------------------
// Dense GEMM: r13's 2-phase 128x128 gemm3 (3-buffer counted vmcnt,
// XCD-chunked 512 blocks, 2-3 blocks/CU — measured ~23 us inside r13).
__global__ __launch_bounds__(256, 3) void gemm_dense(const unsigned short* __restrict__ A,
                                                     const unsigned short* __restrict__ W,
                                                     const float* __restrict__ bias,
                                                     float* __restrict__ out) {
    const int NT = 32;                        // K=1024 / BK=32
    __shared__ unsigned short lsA[3][128 * 32];
    __shared__ unsigned short lsB[3][128 * 32];

    int flat = blockIdx.x;
    int xcd = flat & 7;
    int s = flat >> 3;                        // 0..63
    int brow = (xcd * 8 + (s & 7)) * 128;
    int bcol = (s >> 3) * 128;

    int tid = threadIdx.x;
    int wave = tid >> 6, lane = tid & 63, lg = lane >> 4, l15 = lane & 15;
    int wr = wave >> 1, wc = wave & 1;

    int c0 = wave * 64 + lane, c1 = 256 + c0;
    const unsigned short* sA0 = A + (long)(brow + (c0 >> 2)) * 1024 + ((c0 ^ (c0 >> 2)) & 3) * 8;
    const unsigned short* sA1 = A + (long)(brow + (c1 >> 2)) * 1024 + ((c1 ^ (c1 >> 2)) & 3) * 8;
    const unsigned short* sB0 = W + (long)(bcol + (c0 >> 2)) * 1024 + ((c0 ^ (c0 >> 2)) & 3) * 8;
    const unsigned short* sB1 = W + (long)(bcol + (c1 >> 2)) * 1024 + ((c1 ^ (c1 >> 2)) & 3) * 8;

    int cread = (lg * 16) ^ ((l15 & 3) << 4);

    f32x4 acc[4][4];
#pragma unroll
    for (int m = 0; m < 4; ++m)
#pragma unroll
        for (int n = 0; n < 4; ++n) acc[m][n] = f32x4{0.f, 0.f, 0.f, 0.f};

#define STG(k0, bi) do {                                                  \
        gll16(sA0 + (k0), (char*)lsA[bi] + (wave * 64) * 16);             \
        gll16(sA1 + (k0), (char*)lsA[bi] + (256 + wave * 64) * 16);       \
        gll16(sB0 + (k0), (char*)lsB[bi] + (wave * 64) * 16);             \
        gll16(sB1 + (k0), (char*)lsB[bi] + (256 + wave * 64) * 16);       \
    } while (0)

    STG(0, 0);
    STG(32, 1);

    int bi = 0, sb = 2;
    for (int t = 0; t < NT; ++t) {
        if (t == NT - 1) { asm volatile("s_waitcnt vmcnt(0)" ::: "memory"); }
        else             { asm volatile("s_waitcnt vmcnt(4)" ::: "memory"); }
        __builtin_amdgcn_s_barrier();
        if (t < NT - 2) STG((t + 2) * 32, sb);

        const char* KA = (const char*)lsA[bi];
        const char* KB = (const char*)lsB[bi];
        short8 af[4], bf_[4];
#pragma unroll
        for (int m = 0; m < 4; ++m) {
            int row = wr * 64 + m * 16 + l15;
            af[m] = *(const short8*)(KA + row * 64 + cread);
        }
#pragma unroll
        for (int n = 0; n < 4; ++n) {
            int col = wc * 64 + n * 16 + l15;
            bf_[n] = *(const short8*)(KB + col * 64 + cread);
        }
        __builtin_amdgcn_s_setprio(1);
#pragma unroll
        for (int m = 0; m < 4; ++m)
#pragma unroll
            for (int n = 0; n < 4; ++n) acc[m][n] = MFMA16(af[m], bf_[n], acc[m][n]);
        __builtin_amdgcn_s_setprio(0);

        bi = (bi == 2) ? 0 : bi + 1;
        sb = (sb == 2) ? 0 : sb + 1;
    }
#undef STG

#pragma unroll
    for (int m = 0; m < 4; ++m)
#pragma unroll
        for (int n = 0; n < 4; ++n) {
            int col = bcol + wc * 64 + n * 16 + l15;
            float bv_ = bias[col];
#pragma unroll
            for (int r = 0; r < 4; ++r) {
                int row = brow + wr * 64 + m * 16 + lg * 4 + r;
                out[(long)row * 1024 + col] = acc[m][n][r] + bv_;
            }
        }
}

// ------------------------------------------------------------------
// Flash attention (round-10 version, unchanged).
__global__ __launch_bounds__(256, 2) void attn_kernel(const unsigned short* __restrict__ Qh,
                                                      const unsigned short* __restrict__ Kh,
                                                      const unsigned short* __restrict__ Vt,
                                                      unsigned short* __restrict__ Om) {
    const int S = 2048;
    const int NT = S / 64;
    int flat = blockIdx.x;
    int nf_ = (flat & 7) * 64 + (flat >> 3);
    int qt = nf_ & 7;
    int bh = nf_ >> 3;
    int b = bh >> 4, h = bh & 15;

    int tid = threadIdx.x, wave = tid >> 6, lane = tid & 63;
    int l31 = lane & 31, hi = lane >> 5;

    __shared__ __align__(16) unsigned short Kl[3][4096];
    __shared__ __align__(16) unsigned short Vtl[3][4096];

    const unsigned short* Qb = Qh + (long)bh * S * 64;
    const unsigned short* Kb = Kh + (long)bh * S * 64;
    const unsigned short* Vb = Vt + (long)bh * 64 * S;

    int colS = ((((tid & 7) * 16) ^ (((tid >> 3) & 7) << 4)) >> 1);
    const unsigned short* srcK = Kb + (tid >> 3) * 64 + colS;
    const unsigned short* srcV = Vb + (tid >> 3) * 2048 + colS;

    short8 aq[2][4];
    {
        const unsigned short* qrow = Qb + (long)(qt * 256 + wave * 64 + l31) * 64 + hi * 8;
#pragma unroll
        for (int qf = 0; qf < 2; ++qf)
#pragma unroll
            for (int s = 0; s < 4; ++s)
                aq[qf][s] = *(const short8*)(qrow + qf * 32 * 64 + s * 16);
    }

    f32x16 oacc[2][2], lacc[2], z16;
#pragma unroll
    for (int r = 0; r < 16; ++r) {
        oacc[0][0][r] = 0.f; oacc[0][1][r] = 0.f;
        oacc[1][0][r] = 0.f; oacc[1][1][r] = 0.f;
        lacc[0][r] = 0.f; lacc[1][r] = 0.f;
        z16[r] = 0.f;
    }

    const short8 ones8 = {0x3F80, 0x3F80, 0x3F80, 0x3F80, 0x3F80, 0x3F80, 0x3F80, 0x3F80};
    const unsigned SEL = 0x07060302u;

    int rb0 = l31 * 128;
    int swz = (l31 & 7) << 4;

#define STAGE(kt, bi) do {                                              \
        const unsigned short* sk = srcK + (kt) * 4096;                  \
        gll16(sk,         (char*)Kl[bi] + wave * 1024);                 \
        gll16(sk + 2048,  (char*)Kl[bi] + 4096 + wave * 1024);          \
        const unsigned short* sv = srcV + (kt) * 64;                    \
        gll16(sv,         (char*)Vtl[bi] + wave * 1024);                \
        gll16(sv + 65536, (char*)Vtl[bi] + 4096 + wave * 1024);         \
    } while (0)

    STAGE(0, 0);
    STAGE(1, 1);

    int bi = 0, sb = 2;
    for (int kt = 0; kt < NT; ++kt) {
        if (kt == NT - 1) { asm volatile("s_waitcnt vmcnt(0)" ::: "memory"); }
        else              { asm volatile("s_waitcnt vmcnt(4)" ::: "memory"); }
        __builtin_amdgcn_s_barrier();
        if (kt < NT - 2) STAGE(kt + 2, sb);

        const char* KlC = (const char*)Kl[bi];
        const char* VlC = (const char*)Vtl[bi];

        f32x16 sacc[2][2];
        __builtin_amdgcn_s_setprio(1);
#pragma unroll
        for (int blk = 0; blk < 2; ++blk) {
            short8 kf0 = *(const short8*)(KlC + blk * 4096 + rb0 + ((16 * hi) ^ swz));
            sacc[0][blk] = MFMA32(kf0, aq[0][0], z16);
            sacc[1][blk] = MFMA32(kf0, aq[1][0], z16);
#pragma unroll
            for (int s = 1; s < 4; ++s) {
                short8 kf = *(const short8*)(KlC + blk * 4096 + rb0 + ((32 * s + 16 * hi) ^ swz));
                sacc[0][blk] = MFMA32(kf, aq[0][s], sacc[0][blk]);
                sacc[1][blk] = MFMA32(kf, aq[1][s], sacc[1][blk]);
            }
        }
        __builtin_amdgcn_s_setprio(0);

#pragma unroll
        for (int qf = 0; qf < 2; ++qf)
#pragma unroll
            for (int blk = 0; blk < 2; ++blk)
#pragma unroll
                for (int r = 0; r < 16; ++r) sacc[qf][blk][r] = exp2_fast(sacc[qf][blk][r]);

#pragma unroll
        for (int s = 0; s < 4; ++s) {
            const int blk = s >> 1, base = (s & 1) * 8;
            short8 pa[2];
#pragma unroll
            for (int qf = 0; qf < 2; ++qf) {
                unsigned q0 = pk_perm(sacc[qf][blk][base + 0], sacc[qf][blk][base + 1], SEL);
                unsigned q1 = pk_perm(sacc[qf][blk][base + 2], sacc[qf][blk][base + 3], SEL);
                unsigned q2 = pk_perm(sacc[qf][blk][base + 4], sacc[qf][blk][base + 5], SEL);
                unsigned q3 = pk_perm(sacc[qf][blk][base + 6], sacc[qf][blk][base + 7], SEL);
                pl32_swap(q0, q2);
                pl32_swap(q1, q3);
                uint4v pw; pw[0] = q0; pw[1] = q1; pw[2] = q2; pw[3] = q3;
                pa[qf] = __builtin_bit_cast(short8, pw);
            }
            __builtin_amdgcn_s_setprio(1);
#pragma unroll
            for (int dblk = 0; dblk < 2; ++dblk) {
                short8 vf = *(const short8*)(VlC + dblk * 4096 + rb0 + ((32 * s + 16 * hi) ^ swz));
                oacc[0][dblk] = MFMA32(pa[0], vf, oacc[0][dblk]);
                oacc[1][dblk] = MFMA32(pa[1], vf, oacc[1][dblk]);
            }
            lacc[0] = MFMA32(pa[0], ones8, lacc[0]);
            lacc[1] = MFMA32(pa[1], ones8, lacc[1]);
            __builtin_amdgcn_s_setprio(0);
        }
        bi = (bi == 2) ? 0 : bi + 1;
        sb = (sb == 2) ? 0 : sb + 1;
    }
#undef STAGE

#pragma unroll
    for (int qf = 0; qf < 2; ++qf) {
        float inv[16];
#pragma unroll
        for (int r = 0; r < 16; ++r) inv[r] = 1.0f / lacc[qf][r];
        int qrow0 = qt * 256 + wave * 64 + qf * 32 + 4 * hi;
#pragma unroll
        for (int dblk = 0; dblk < 2; ++dblk)
#pragma unroll
            for (int r = 0; r < 16; ++r) {
                int qrow = qrow0 + (r & 3) + 8 * (r >> 2);
                int d = h * 64 + dblk * 32 + l31;
                float v = oacc[qf][dblk][r] * inv[r];
                Om[((long)b * 2048 + qrow) * 1024 + d] = f2bf(v);
            }
    }
}

// ------------------------------------------------------------------
extern "C" void kernel_launch(void* const* d_in, const int* in_sizes, int n_in,
                              void* d_out, int out_size, void* d_ws, size_t ws_size,
                              hipStream_t stream) {
    const float* v_in = (const float*)d_in[0];
    const float* k_in = (const float*)d_in[1];
    const float* q_in = (const float*)d_in[2];
    const float* wq_w = (const float*)d_in[3];
    const float* wq_b = (const float*)d_in[4];
    const float* wk_w = (const float*)d_in[5];
    const float* wk_b = (const float*)d_in[6];
    const float* wv_w = (const float*)d_in[7];
    const float* wv_b = (const float*)d_in[8];
    const float* wd_w = (const float*)d_in[9];
    const float* wd_b = (const float*)d_in[10];
    const float* pe   = (const float*)d_in[11];

    const long SZ = 8192L * 1024 * 2;
    char* ws = (char*)d_ws;
    unsigned short* xq = (unsigned short*)(ws + 0);          // xq,xk,xv contiguous
    unsigned short* xk = (unsigned short*)(ws + SZ);
    unsigned short* xv = (unsigned short*)(ws + 2 * SZ);
    unsigned short* qh = (unsigned short*)(ws + 3 * SZ);
    unsigned short* kh = (unsigned short*)(ws + 4 * SZ);
    unsigned short* vt = (unsigned short*)(ws + 5 * SZ);
    unsigned short* wqb16 = (unsigned short*)(ws + 6 * SZ);  // wq,wk,wv,wd contiguous

    pe_cast3<<<dim3(8192, 3), 256, 0, stream>>>(q_in, k_in, v_in, pe, xq, xk, xv);
    wcast4<<<dim3(1024, 4), 256, 0, stream>>>(wq_w, wk_w, wv_w, wd_w, wqb16);

    const float QSCALE = 0.125f * 1.44269504088896f;   // fold 1/sqrt(64) * log2(e)
    // Q/K/V projections: 256x256 tiles, 8-phase schedule, 384 blocks
    gemm8<<<dim3(32, 4, 3), 512, 0, stream>>>(
        xq, wqb16, wq_b, wk_b, wv_b, qh, kh, vt, QSCALE);

    unsigned short* om = xq;
    attn_kernel<<<512, 256, 0, stream>>>(qh, kh, vt, om);

    // dense: 2-phase 128x128, 512 blocks XCD-chunked (r13-proven ~23 us)
    gemm_dense<<<512, 256, 0, stream>>>(
        om, wqb16 + 3L * 1024 * 1024, wd_b, (float*)d_out);
}

// Round 16
// 203.349 us; speedup vs baseline: 1.0629x; 1.0106x over previous
//
#include <hip/hip_runtime.h>
#include <hip/hip_bf16.h>

typedef short short8 __attribute__((ext_vector_type(8)));
typedef float f32x4 __attribute__((ext_vector_type(4)));
typedef float f32x16 __attribute__((ext_vector_type(16)));
typedef unsigned int uint4v __attribute__((ext_vector_type(4)));

#define MFMA16(a, b, c) __builtin_amdgcn_mfma_f32_16x16x32_bf16(a, b, c, 0, 0, 0)
#define MFMA32(a, b, c) __builtin_amdgcn_mfma_f32_32x32x16_bf16(a, b, c, 0, 0, 0)

typedef __attribute__((address_space(1))) const unsigned int gas_u32;
typedef __attribute__((address_space(3))) unsigned int las_u32;

__device__ inline void gll16(const void* g, void* l) {
    __builtin_amdgcn_global_load_lds((gas_u32*)g, (las_u32*)l, 16, 0, 0);
}

__device__ inline unsigned short f2bf(float f) {
    unsigned u = __builtin_bit_cast(unsigned, f);
    u += 0x7fff + ((u >> 16) & 1);   // RNE (inputs finite)
    return (unsigned short)(u >> 16);
}

__device__ inline unsigned pk_perm(float a, float b, unsigned sel) {
    unsigned r;
    asm("v_perm_b32 %0, %1, %2, %3"
        : "=v"(r)
        : "v"(__builtin_bit_cast(unsigned, b)), "v"(__builtin_bit_cast(unsigned, a)), "s"(sel));
    return r;
}

__device__ inline float exp2_fast(float x) {
#if __has_builtin(__builtin_amdgcn_exp2f)
    return __builtin_amdgcn_exp2f(x);
#else
    float r; asm("v_exp_f32 %0, %1" : "=v"(r) : "v"(x)); return r;
#endif
}

__device__ inline void pl32_swap(unsigned &a, unsigned &b) {
    asm volatile("v_permlane32_swap_b32 %0, %1" : "+v"(a), "+v"(b));
}

// ------------------------------------------------------------------
__global__ void pe_cast3(const float* __restrict__ q, const float* __restrict__ k,
                         const float* __restrict__ v, const float* __restrict__ pe,
                         unsigned short* __restrict__ oq, unsigned short* __restrict__ ok,
                         unsigned short* __restrict__ ov) {
    const float* x = (blockIdx.y == 0) ? q : (blockIdx.y == 1) ? k : v;
    unsigned short* o = (blockIdx.y == 0) ? oq : (blockIdx.y == 1) ? ok : ov;
    int i = blockIdx.x * 256 + threadIdx.x;
    long e = (long)i * 4;
    int b = (int)(e >> 21);
    int d = (int)(e & 1023);
    float4 xv = reinterpret_cast<const float4*>(x)[i];
    float4 pv = *reinterpret_cast<const float4*>(pe + b * 1024 + d);
    ushort4 r;
    r.x = f2bf(xv.x + pv.x); r.y = f2bf(xv.y + pv.y);
    r.z = f2bf(xv.z + pv.z); r.w = f2bf(xv.w + pv.w);
    reinterpret_cast<ushort4*>(o)[i] = r;
}

__global__ void wcast4(const float* __restrict__ w0, const float* __restrict__ w1,
                       const float* __restrict__ w2, const float* __restrict__ w3,
                       unsigned short* __restrict__ o0) {
    const float* w = (blockIdx.y == 0) ? w0 : (blockIdx.y == 1) ? w1
                   : (blockIdx.y == 2) ? w2 : w3;
    unsigned short* o = o0 + (size_t)blockIdx.y * 1024 * 1024;
    int i = blockIdx.x * 256 + threadIdx.x;
    float4 xv = reinterpret_cast<const float4*>(w)[i];
    ushort4 r;
    r.x = f2bf(xv.x); r.y = f2bf(xv.y); r.z = f2bf(xv.z); r.w = f2bf(xv.w);
    reinterpret_cast<ushort4*>(o)[i] = r;
}

// ------------------------------------------------------------------
// gemm8p: persistent QKV projection, 256 blocks x 512 thr, 2 assignments each.
// Assignment 1 (blk 0..255): full 256x256 8-phase tile of Q-proj (z=0, blk<128)
//   or K-proj (z=1) — exact r14/r15-verified schedule.
// Assignment 2: half-tile 256x128 of V-proj (z=2), tile ti=blk>>1, half=blk&1;
//   4x2 wave grid (64x64 wave-tile), T3-minimum loop: stage-6-then-vmcnt(6),
//   one barrier pair per K-tile, counted vmcnt (0 only at tail).
__global__ __launch_bounds__(512, 2) void gemm8p(const unsigned short* __restrict__ A0,
                                                 const unsigned short* __restrict__ W0,
                                                 const float* __restrict__ bq,
                                                 const float* __restrict__ bk,
                                                 const float* __restrict__ bv,
                                                 unsigned short* __restrict__ oq,
                                                 unsigned short* __restrict__ ok,
                                                 unsigned short* __restrict__ ov,
                                                 float qscale) {
    const int NT = 16;                        // K=1024 / BK=64
    __shared__ __align__(16) unsigned short lsA[2][256 * 64];
    __shared__ __align__(16) unsigned short lsB[2][256 * 64];

    int blk = blockIdx.x;
    int tid = threadIdx.x, wave = tid >> 6, lane = tid & 63;
    int lg = lane >> 4, l15 = lane & 15;
    int srow = tid >> 3;
    int scol = ((tid ^ srow) & 7) * 8;        // pre-swizzled source col (elems)
    int swz_ = (l15 & 7) << 4;

    // ================= Assignment 1: full 256^2 tile, z = blk>>7 =================
    {
        int z = blk >> 7;                     // 0 or 1
        int rem = blk & 127;
        int brow = (rem >> 2) * 256;
        int bcol = (rem & 3) * 256;
        const unsigned short* A = A0 + (size_t)z * 8192 * 1024;
        const unsigned short* W = W0 + (size_t)z * 1024 * 1024;
        const float* bias = (z == 0) ? bq : bk;
        float scale = (z == 0) ? qscale : 1.0f;
        unsigned short* out = (z == 0) ? oq : ok;

        int wr = wave >> 2, wc = wave & 3;    // 2 x 4 wave grid
        const unsigned short* pA = A + (long)(brow + srow) * 1024 + scol;
        const unsigned short* pB = W + (long)(bcol + srow) * 1024 + scol;

        f32x4 acc[8][4];
#pragma unroll
        for (int m = 0; m < 8; ++m)
#pragma unroll
            for (int n = 0; n < 4; ++n) acc[m][n] = f32x4{0.f, 0.f, 0.f, 0.f};

#define SA(t, bi, q) gll16(pA + (t) * 64 + (q) * 65536,                     \
                           (char*)lsA[bi] + ((q) * 512 + wave * 64) * 16)
#define SB(t, bi, q) gll16(pB + (t) * 64 + (q) * 65536,                     \
                           (char*)lsB[bi] + ((q) * 512 + wave * 64) * 16)

        SB(0, 0, 0); SB(0, 0, 1); SB(0, 0, 2); SB(0, 0, 3);
        SA(0, 0, 0); SA(0, 0, 2); SA(0, 0, 1); SA(0, 0, 3);
        asm volatile("s_waitcnt vmcnt(2)" ::: "memory");
        __builtin_amdgcn_s_barrier();

        for (int t = 0; t < NT; ++t) {
            int cb = t & 1, nb = cb ^ 1;
            const char* KA = (const char*)lsA[cb];
            const char* KB = (const char*)lsB[cb];
            short8 af0[4][2], af1[4][2], bf0[2][2], bf1[2][2];
            const bool st = (t < NT - 1);

            // q1: (m0-3, n0-1)
#pragma unroll
            for (int m = 0; m < 4; ++m)
#pragma unroll
                for (int kk = 0; kk < 2; ++kk)
                    af0[m][kk] = *(const short8*)(KA + (wr * 128 + m * 16 + l15) * 128 +
                                                  (((kk * 4 + lg) << 4) ^ swz_));
#pragma unroll
            for (int n = 0; n < 2; ++n)
#pragma unroll
                for (int kk = 0; kk < 2; ++kk)
                    bf0[n][kk] = *(const short8*)(KB + (wc * 64 + n * 16 + l15) * 128 +
                                                  (((kk * 4 + lg) << 4) ^ swz_));
            if (st) { SB(t + 1, nb, 0); SB(t + 1, nb, 1); }
            __builtin_amdgcn_s_barrier();
            asm volatile("s_waitcnt lgkmcnt(0)" ::: "memory");
            __builtin_amdgcn_s_setprio(1);
#pragma unroll
            for (int m = 0; m < 4; ++m)
#pragma unroll
                for (int n = 0; n < 2; ++n)
#pragma unroll
                    for (int kk = 0; kk < 2; ++kk)
                        acc[m][n] = MFMA16(af0[m][kk], bf0[n][kk], acc[m][n]);
            __builtin_amdgcn_s_setprio(0);
            __builtin_amdgcn_s_barrier();

            // q2: (m0-3, n2-3)
#pragma unroll
            for (int n = 0; n < 2; ++n)
#pragma unroll
                for (int kk = 0; kk < 2; ++kk)
                    bf1[n][kk] = *(const short8*)(KB + (wc * 64 + (n + 2) * 16 + l15) * 128 +
                                                  (((kk * 4 + lg) << 4) ^ swz_));
            if (st) { SB(t + 1, nb, 2); SB(t + 1, nb, 3); }
            if (st) { asm volatile("s_waitcnt vmcnt(4)" ::: "memory"); }
            else    { asm volatile("s_waitcnt vmcnt(0)" ::: "memory"); }
            __builtin_amdgcn_s_barrier();
            asm volatile("s_waitcnt lgkmcnt(0)" ::: "memory");
            __builtin_amdgcn_s_setprio(1);
#pragma unroll
            for (int m = 0; m < 4; ++m)
#pragma unroll
                for (int n = 0; n < 2; ++n)
#pragma unroll
                    for (int kk = 0; kk < 2; ++kk)
                        acc[m][n + 2] = MFMA16(af0[m][kk], bf1[n][kk], acc[m][n + 2]);
            __builtin_amdgcn_s_setprio(0);
            __builtin_amdgcn_s_barrier();

            // q3: (m4-7, n0-1)
#pragma unroll
            for (int m = 0; m < 4; ++m)
#pragma unroll
                for (int kk = 0; kk < 2; ++kk)
                    af1[m][kk] = *(const short8*)(KA + (wr * 128 + (m + 4) * 16 + l15) * 128 +
                                                  (((kk * 4 + lg) << 4) ^ swz_));
            if (st) { SA(t + 1, nb, 0); SA(t + 1, nb, 2); }
            __builtin_amdgcn_s_barrier();
            asm volatile("s_waitcnt lgkmcnt(0)" ::: "memory");
            __builtin_amdgcn_s_setprio(1);
#pragma unroll
            for (int m = 0; m < 4; ++m)
#pragma unroll
                for (int n = 0; n < 2; ++n)
#pragma unroll
                    for (int kk = 0; kk < 2; ++kk)
                        acc[m + 4][n] = MFMA16(af1[m][kk], bf0[n][kk], acc[m + 4][n]);
            __builtin_amdgcn_s_setprio(0);
            __builtin_amdgcn_s_barrier();

            // q4: (m4-7, n2-3)
            if (st) {
                SA(t + 1, nb, 1); SA(t + 1, nb, 3);
                asm volatile("s_waitcnt vmcnt(2)" ::: "memory");
            }
            __builtin_amdgcn_s_barrier();
            __builtin_amdgcn_s_setprio(1);
#pragma unroll
            for (int m = 0; m < 4; ++m)
#pragma unroll
                for (int n = 0; n < 2; ++n)
#pragma unroll
                    for (int kk = 0; kk < 2; ++kk)
                        acc[m + 4][n + 2] = MFMA16(af1[m][kk], bf1[n][kk], acc[m + 4][n + 2]);
            __builtin_amdgcn_s_setprio(0);
            __builtin_amdgcn_s_barrier();
        }
#undef SA
#undef SB

        // epilogue: head-split bf16
#pragma unroll
        for (int m = 0; m < 8; ++m)
#pragma unroll
            for (int n = 0; n < 4; ++n) {
                int col = bcol + wc * 64 + n * 16 + l15;
                float bv_ = bias[col];
                int row0 = brow + wr * 128 + m * 16 + lg * 4;
#pragma unroll
                for (int r = 0; r < 4; ++r) {
                    int row = row0 + r;
                    float v = (acc[m][n][r] + bv_) * scale;
                    int b = row >> 11, s = row & 2047, h = col >> 6, d = col & 63;
                    out[(((long)(b * 16 + h) * 2048 + s) * 64 + d)] = f2bf(v);
                }
            }
    }

    // ================= Assignment 2: half-tile 256x128 of V-proj (z=2) ===========
    {
        int ti = blk >> 1;                    // 0..127
        int brow = (ti >> 2) * 256;
        int bcol = (ti & 3) * 256 + (blk & 1) * 128;
        const unsigned short* A = A0 + (size_t)2 * 8192 * 1024;
        const unsigned short* W = W0 + (size_t)2 * 1024 * 1024;

        int wr = wave >> 1, wc = wave & 1;    // 4 x 2 wave grid, 64x64 wave tile
        const unsigned short* pA = A + (long)(brow + srow) * 1024 + scol;
        const unsigned short* pB = W + (long)(bcol + srow) * 1024 + scol;

        f32x4 acc[4][4];
#pragma unroll
        for (int m = 0; m < 4; ++m)
#pragma unroll
            for (int n = 0; n < 4; ++n) acc[m][n] = f32x4{0.f, 0.f, 0.f, 0.f};

#define SA2(t, bi, q) gll16(pA + (t) * 64 + (q) * 65536,                     \
                            (char*)lsA[bi] + ((q) * 512 + wave * 64) * 16)
#define SB2(t, bi, q) gll16(pB + (t) * 64 + (q) * 65536,                     \
                            (char*)lsB[bi] + ((q) * 512 + wave * 64) * 16)

        // prologue: tile 0's 6 units (A 4, B 2)
        SB2(0, 0, 0); SB2(0, 0, 1);
        SA2(0, 0, 0); SA2(0, 0, 1); SA2(0, 0, 2); SA2(0, 0, 3);

        for (int t = 0; t < NT; ++t) {
            int cb = t & 1, nb = cb ^ 1;
            // stage t+1 FIRST (buffer nb: its reads ended at t-1's closing barrier)
            if (t < NT - 1) {
                SB2(t + 1, nb, 0); SB2(t + 1, nb, 1);
                SA2(t + 1, nb, 0); SA2(t + 1, nb, 1); SA2(t + 1, nb, 2); SA2(t + 1, nb, 3);
                asm volatile("s_waitcnt vmcnt(6)" ::: "memory");   // t's 6 done
            } else {
                asm volatile("s_waitcnt vmcnt(0)" ::: "memory");
            }
            __builtin_amdgcn_s_barrier();

            const char* KA = (const char*)lsA[cb];
            const char* KB = (const char*)lsB[cb];
            short8 af[4][2], bf[4][2];
#pragma unroll
            for (int m = 0; m < 4; ++m)
#pragma unroll
                for (int kk = 0; kk < 2; ++kk)
                    af[m][kk] = *(const short8*)(KA + (wr * 64 + m * 16 + l15) * 128 +
                                                 (((kk * 4 + lg) << 4) ^ swz_));
#pragma unroll
            for (int n = 0; n < 4; ++n)
#pragma unroll
                for (int kk = 0; kk < 2; ++kk)
                    bf[n][kk] = *(const short8*)(KB + (wc * 64 + n * 16 + l15) * 128 +
                                                 (((kk * 4 + lg) << 4) ^ swz_));
            __builtin_amdgcn_s_setprio(1);
#pragma unroll
            for (int m = 0; m < 4; ++m)
#pragma unroll
                for (int n = 0; n < 4; ++n)
#pragma unroll
                    for (int kk = 0; kk < 2; ++kk)
                        acc[m][n] = MFMA16(af[m][kk], bf[n][kk], acc[m][n]);
            __builtin_amdgcn_s_setprio(0);
            __builtin_amdgcn_s_barrier();
        }
#undef SA2
#undef SB2

        // epilogue: V^T [B][1024col][2048s], ushort4 pack (4 consecutive s per lane)
#pragma unroll
        for (int m = 0; m < 4; ++m)
#pragma unroll
            for (int n = 0; n < 4; ++n) {
                int col = bcol + wc * 64 + n * 16 + l15;
                float bv_ = bv[col];
                int row0 = brow + wr * 64 + m * 16 + lg * 4;
                int b = row0 >> 11, s0 = row0 & 2047;
                ushort4 pk;
                pk.x = f2bf(acc[m][n][0] + bv_);
                pk.y = f2bf(acc[m][n][1] + bv_);
                pk.z = f2bf(acc[m][n][2] + bv_);
                pk.w = f2bf(acc[m][n][3] + bv_);
                *(ushort4*)(ov + ((long)(b * 1024 + col)) * 2048 + s0) = pk;
            }
    }
}

// ------------------------------------------------------------------
// Dense GEMM: r13's 2-phase 128x128 (3-buffer counted vmcnt, XCD-chunked,
// 512 blocks — measured ~23 us).
__global__ __launch_bounds__(256, 3) void gemm_dense(const unsigned short* __restrict__ A,
                                                     const unsigned short* __restrict__ W,
                                                     const float* __restrict__ bias,
                                                     float* __restrict__ out) {
    const int NT = 32;                        // K=1024 / BK=32
    __shared__ unsigned short lsA[3][128 * 32];
    __shared__ unsigned short lsB[3][128 * 32];

    int flat = blockIdx.x;
    int xcd = flat & 7;
    int s = flat >> 3;
    int brow = (xcd * 8 + (s & 7)) * 128;
    int bcol = (s >> 3) * 128;

    int tid = threadIdx.x;
    int wave = tid >> 6, lane = tid & 63, lg = lane >> 4, l15 = lane & 15;
    int wr = wave >> 1, wc = wave & 1;

    int c0 = wave * 64 + lane, c1 = 256 + c0;
    const unsigned short* sA0 = A + (long)(brow + (c0 >> 2)) * 1024 + ((c0 ^ (c0 >> 2)) & 3) * 8;
    const unsigned short* sA1 = A + (long)(brow + (c1 >> 2)) * 1024 + ((c1 ^ (c1 >> 2)) & 3) * 8;
    const unsigned short* sB0 = W + (long)(bcol + (c0 >> 2)) * 1024 + ((c0 ^ (c0 >> 2)) & 3) * 8;
    const unsigned short* sB1 = W + (long)(bcol + (c1 >> 2)) * 1024 + ((c1 ^ (c1 >> 2)) & 3) * 8;

    int cread = (lg * 16) ^ ((l15 & 3) << 4);

    f32x4 acc[4][4];
#pragma unroll
    for (int m = 0; m < 4; ++m)
#pragma unroll
        for (int n = 0; n < 4; ++n) acc[m][n] = f32x4{0.f, 0.f, 0.f, 0.f};

#define STG(k0, bi) do {                                                  \
        gll16(sA0 + (k0), (char*)lsA[bi] + (wave * 64) * 16);             \
        gll16(sA1 + (k0), (char*)lsA[bi] + (256 + wave * 64) * 16);       \
        gll16(sB0 + (k0), (char*)lsB[bi] + (wave * 64) * 16);             \
        gll16(sB1 + (k0), (char*)lsB[bi] + (256 + wave * 64) * 16);       \
    } while (0)

    STG(0, 0);
    STG(32, 1);

    int bi = 0, sb = 2;
    for (int t = 0; t < NT; ++t) {
        if (t == NT - 1) { asm volatile("s_waitcnt vmcnt(0)" ::: "memory"); }
        else             { asm volatile("s_waitcnt vmcnt(4)" ::: "memory"); }
        __builtin_amdgcn_s_barrier();
        if (t < NT - 2) STG((t + 2) * 32, sb);

        const char* KA = (const char*)lsA[bi];
        const char* KB = (const char*)lsB[bi];
        short8 af[4], bf_[4];
#pragma unroll
        for (int m = 0; m < 4; ++m) {
            int row = wr * 64 + m * 16 + l15;
            af[m] = *(const short8*)(KA + row * 64 + cread);
        }
#pragma unroll
        for (int n = 0; n < 4; ++n) {
            int col = wc * 64 + n * 16 + l15;
            bf_[n] = *(const short8*)(KB + col * 64 + cread);
        }
        __builtin_amdgcn_s_setprio(1);
#pragma unroll
        for (int m = 0; m < 4; ++m)
#pragma unroll
            for (int n = 0; n < 4; ++n) acc[m][n] = MFMA16(af[m], bf_[n], acc[m][n]);
        __builtin_amdgcn_s_setprio(0);

        bi = (bi == 2) ? 0 : bi + 1;
        sb = (sb == 2) ? 0 : sb + 1;
    }
#undef STG

#pragma unroll
    for (int m = 0; m < 4; ++m)
#pragma unroll
        for (int n = 0; n < 4; ++n) {
            int col = bcol + wc * 64 + n * 16 + l15;
            float bv_ = bias[col];
#pragma unroll
            for (int r = 0; r < 4; ++r) {
                int row = brow + wr * 64 + m * 16 + lg * 4 + r;
                out[(long)row * 1024 + col] = acc[m][n][r] + bv_;
            }
        }
}

// ------------------------------------------------------------------
// Flash attention (round-10 version, unchanged).
__global__ __launch_bounds__(256, 2) void attn_kernel(const unsigned short* __restrict__ Qh,
                                                      const unsigned short* __restrict__ Kh,
                                                      const unsigned short* __restrict__ Vt,
                                                      unsigned short* __restrict__ Om) {
    const int S = 2048;
    const int NT = S / 64;
    int flat = blockIdx.x;
    int nf_ = (flat & 7) * 64 + (flat >> 3);
    int qt = nf_ & 7;
    int bh = nf_ >> 3;
    int b = bh >> 4, h = bh & 15;

    int tid = threadIdx.x, wave = tid >> 6, lane = tid & 63;
    int l31 = lane & 31, hi = lane >> 5;

    __shared__ __align__(16) unsigned short Kl[3][4096];
    __shared__ __align__(16) unsigned short Vtl[3][4096];

    const unsigned short* Qb = Qh + (long)bh * S * 64;
    const unsigned short* Kb = Kh + (long)bh * S * 64;
    const unsigned short* Vb = Vt + (long)bh * 64 * S;

    int colS = ((((tid & 7) * 16) ^ (((tid >> 3) & 7) << 4)) >> 1);
    const unsigned short* srcK = Kb + (tid >> 3) * 64 + colS;
    const unsigned short* srcV = Vb + (tid >> 3) * 2048 + colS;

    short8 aq[2][4];
    {
        const unsigned short* qrow = Qb + (long)(qt * 256 + wave * 64 + l31) * 64 + hi * 8;
#pragma unroll
        for (int qf = 0; qf < 2; ++qf)
#pragma unroll
            for (int s = 0; s < 4; ++s)
                aq[qf][s] = *(const short8*)(qrow + qf * 32 * 64 + s * 16);
    }

    f32x16 oacc[2][2], lacc[2], z16;
#pragma unroll
    for (int r = 0; r < 16; ++r) {
        oacc[0][0][r] = 0.f; oacc[0][1][r] = 0.f;
        oacc[1][0][r] = 0.f; oacc[1][1][r] = 0.f;
        lacc[0][r] = 0.f; lacc[1][r] = 0.f;
        z16[r] = 0.f;
    }

    const short8 ones8 = {0x3F80, 0x3F80, 0x3F80, 0x3F80, 0x3F80, 0x3F80, 0x3F80, 0x3F80};
    const unsigned SEL = 0x07060302u;

    int rb0 = l31 * 128;
    int swz = (l31 & 7) << 4;

#define STAGE(kt, bi) do {                                              \
        const unsigned short* sk = srcK + (kt) * 4096;                  \
        gll16(sk,         (char*)Kl[bi] + wave * 1024);                 \
        gll16(sk + 2048,  (char*)Kl[bi] + 4096 + wave * 1024);          \
        const unsigned short* sv = srcV + (kt) * 64;                    \
        gll16(sv,         (char*)Vtl[bi] + wave * 1024);                \
        gll16(sv + 65536, (char*)Vtl[bi] + 4096 + wave * 1024);         \
    } while (0)

    STAGE(0, 0);
    STAGE(1, 1);

    int bi = 0, sb = 2;
    for (int kt = 0; kt < NT; ++kt) {
        if (kt == NT - 1) { asm volatile("s_waitcnt vmcnt(0)" ::: "memory"); }
        else              { asm volatile("s_waitcnt vmcnt(4)" ::: "memory"); }
        __builtin_amdgcn_s_barrier();
        if (kt < NT - 2) STAGE(kt + 2, sb);

        const char* KlC = (const char*)Kl[bi];
        const char* VlC = (const char*)Vtl[bi];

        f32x16 sacc[2][2];
        __builtin_amdgcn_s_setprio(1);
#pragma unroll
        for (int blk = 0; blk < 2; ++blk) {
            short8 kf0 = *(const short8*)(KlC + blk * 4096 + rb0 + ((16 * hi) ^ swz));
            sacc[0][blk] = MFMA32(kf0, aq[0][0], z16);
            sacc[1][blk] = MFMA32(kf0, aq[1][0], z16);
#pragma unroll
            for (int s = 1; s < 4; ++s) {
                short8 kf = *(const short8*)(KlC + blk * 4096 + rb0 + ((32 * s + 16 * hi) ^ swz));
                sacc[0][blk] = MFMA32(kf, aq[0][s], sacc[0][blk]);
                sacc[1][blk] = MFMA32(kf, aq[1][s], sacc[1][blk]);
            }
        }
        __builtin_amdgcn_s_setprio(0);

#pragma unroll
        for (int qf = 0; qf < 2; ++qf)
#pragma unroll
            for (int blk = 0; blk < 2; ++blk)
#pragma unroll
                for (int r = 0; r < 16; ++r) sacc[qf][blk][r] = exp2_fast(sacc[qf][blk][r]);

#pragma unroll
        for (int s = 0; s < 4; ++s) {
            const int blk = s >> 1, base = (s & 1) * 8;
            short8 pa[2];
#pragma unroll
            for (int qf = 0; qf < 2; ++qf) {
                unsigned q0 = pk_perm(sacc[qf][blk][base + 0], sacc[qf][blk][base + 1], SEL);
                unsigned q1 = pk_perm(sacc[qf][blk][base + 2], sacc[qf][blk][base + 3], SEL);
                unsigned q2 = pk_perm(sacc[qf][blk][base + 4], sacc[qf][blk][base + 5], SEL);
                unsigned q3 = pk_perm(sacc[qf][blk][base + 6], sacc[qf][blk][base + 7], SEL);
                pl32_swap(q0, q2);
                pl32_swap(q1, q3);
                uint4v pw; pw[0] = q0; pw[1] = q1; pw[2] = q2; pw[3] = q3;
                pa[qf] = __builtin_bit_cast(short8, pw);
            }
            __builtin_amdgcn_s_setprio(1);
#pragma unroll
            for (int dblk = 0; dblk < 2; ++dblk) {
                short8 vf = *(const short8*)(VlC + dblk * 4096 + rb0 + ((32 * s + 16 * hi) ^ swz));
                oacc[0][dblk] = MFMA32(pa[0], vf, oacc[0][dblk]);
                oacc[1][dblk] = MFMA32(pa[1], vf, oacc[1][dblk]);
            }
            lacc[0] = MFMA32(pa[0], ones8, lacc[0]);
            lacc[1] = MFMA32(pa[1], ones8, lacc[1]);
            __builtin_amdgcn_s_setprio(0);
        }
        bi = (bi == 2) ? 0 : bi + 1;
        sb = (sb == 2) ? 0 : sb + 1;
    }
#undef STAGE

#pragma unroll
    for (int qf = 0; qf < 2; ++qf) {
        float inv[16];
#pragma unroll
        for (int r = 0; r < 16; ++r) inv[r] = 1.0f / lacc[qf][r];
        int qrow0 = qt * 256 + wave * 64 + qf * 32 + 4 * hi;
#pragma unroll
        for (int dblk = 0; dblk < 2; ++dblk)
#pragma unroll
            for (int r = 0; r < 16; ++r) {
                int qrow = qrow0 + (r & 3) + 8 * (r >> 2);
                int d = h * 64 + dblk * 32 + l31;
                float v = oacc[qf][dblk][r] * inv[r];
                Om[((long)b * 2048 + qrow) * 1024 + d] = f2bf(v);
            }
    }
}

// ------------------------------------------------------------------
extern "C" void kernel_launch(void* const* d_in, const int* in_sizes, int n_in,
                              void* d_out, int out_size, void* d_ws, size_t ws_size,
                              hipStream_t stream) {
    const float* v_in = (const float*)d_in[0];
    const float* k_in = (const float*)d_in[1];
    const float* q_in = (const float*)d_in[2];
    const float* wq_w = (const float*)d_in[3];
    const float* wq_b = (const float*)d_in[4];
    const float* wk_w = (const float*)d_in[5];
    const float* wk_b = (const float*)d_in[6];
    const float* wv_w = (const float*)d_in[7];
    const float* wv_b = (const float*)d_in[8];
    const float* wd_w = (const float*)d_in[9];
    const float* wd_b = (const float*)d_in[10];
    const float* pe   = (const float*)d_in[11];

    const long SZ = 8192L * 1024 * 2;
    char* ws = (char*)d_ws;
    unsigned short* xq = (unsigned short*)(ws + 0);          // xq,xk,xv contiguous
    unsigned short* xk = (unsigned short*)(ws + SZ);
    unsigned short* xv = (unsigned short*)(ws + 2 * SZ);
    unsigned short* qh = (unsigned short*)(ws + 3 * SZ);
    unsigned short* kh = (unsigned short*)(ws + 4 * SZ);
    unsigned short* vt = (unsigned short*)(ws + 5 * SZ);
    unsigned short* wqb16 = (unsigned short*)(ws + 6 * SZ);  // wq,wk,wv,wd contiguous

    pe_cast3<<<dim3(8192, 3), 256, 0, stream>>>(q_in, k_in, v_in, pe, xq, xk, xv);
    wcast4<<<dim3(1024, 4), 256, 0, stream>>>(wq_w, wk_w, wv_w, wd_w, wqb16);

    const float QSCALE = 0.125f * 1.44269504088896f;   // fold 1/sqrt(64) * log2(e)
    // Q/K/V projections: persistent 256 blocks, full tile (z=0/1) + V half-tile
    gemm8p<<<256, 512, 0, stream>>>(
        xq, wqb16, wq_b, wk_b, wv_b, qh, kh, vt, QSCALE);

    unsigned short* om = xq;
    attn_kernel<<<512, 256, 0, stream>>>(qh, kh, vt, om);

    gemm_dense<<<512, 256, 0, stream>>>(
        om, wqb16 + 3L * 1024 * 1024, wd_b, (float*)d_out);
}

// Round 17
// 201.094 us; speedup vs baseline: 1.0748x; 1.0112x over previous
//
#include <hip/hip_runtime.h>
#include <hip/hip_bf16.h>

typedef short short8 __attribute__((ext_vector_type(8)));
typedef float f32x4 __attribute__((ext_vector_type(4)));
typedef float f32x16 __attribute__((ext_vector_type(16)));
typedef unsigned int uint4v __attribute__((ext_vector_type(4)));

#define MFMA16(a, b, c) __builtin_amdgcn_mfma_f32_16x16x32_bf16(a, b, c, 0, 0, 0)
#define MFMA32(a, b, c) __builtin_amdgcn_mfma_f32_32x32x16_bf16(a, b, c, 0, 0, 0)

typedef __attribute__((address_space(1))) const unsigned int gas_u32;
typedef __attribute__((address_space(3))) unsigned int las_u32;

__device__ inline void gll16(const void* g, void* l) {
    __builtin_amdgcn_global_load_lds((gas_u32*)g, (las_u32*)l, 16, 0, 0);
}

__device__ inline unsigned short f2bf(float f) {
    unsigned u = __builtin_bit_cast(unsigned, f);
    u += 0x7fff + ((u >> 16) & 1);   // RNE (inputs finite)
    return (unsigned short)(u >> 16);
}

__device__ inline unsigned pk_perm(float a, float b, unsigned sel) {
    unsigned r;
    asm("v_perm_b32 %0, %1, %2, %3"
        : "=v"(r)
        : "v"(__builtin_bit_cast(unsigned, b)), "v"(__builtin_bit_cast(unsigned, a)), "s"(sel));
    return r;
}

__device__ inline float exp2_fast(float x) {
#if __has_builtin(__builtin_amdgcn_exp2f)
    return __builtin_amdgcn_exp2f(x);
#else
    float r; asm("v_exp_f32 %0, %1" : "=v"(r) : "v"(x)); return r;
#endif
}

__device__ inline void pl32_swap(unsigned &a, unsigned &b) {
    asm volatile("v_permlane32_swap_b32 %0, %1" : "+v"(a), "+v"(b));
}

// ------------------------------------------------------------------
// Merged stage 1: pe-add+cast (y=0..2) and weight cast (y=3).
__global__ void pe_wcast(const float* __restrict__ q, const float* __restrict__ k,
                         const float* __restrict__ v, const float* __restrict__ pe,
                         const float* __restrict__ w0, const float* __restrict__ w1,
                         const float* __restrict__ w2, const float* __restrict__ w3,
                         unsigned short* __restrict__ oq, unsigned short* __restrict__ ok,
                         unsigned short* __restrict__ ov, unsigned short* __restrict__ ow) {
    if (blockIdx.y == 3) {
        if (blockIdx.x >= 4096) return;
        int wsel = blockIdx.x >> 10;
        const float* w = (wsel == 0) ? w0 : (wsel == 1) ? w1 : (wsel == 2) ? w2 : w3;
        unsigned short* o = ow + (size_t)wsel * 1024 * 1024;
        int i = (blockIdx.x & 1023) * 256 + threadIdx.x;
        float4 xv = reinterpret_cast<const float4*>(w)[i];
        ushort4 r;
        r.x = f2bf(xv.x); r.y = f2bf(xv.y); r.z = f2bf(xv.z); r.w = f2bf(xv.w);
        reinterpret_cast<ushort4*>(o)[i] = r;
        return;
    }
    const float* x = (blockIdx.y == 0) ? q : (blockIdx.y == 1) ? k : v;
    unsigned short* o = (blockIdx.y == 0) ? oq : (blockIdx.y == 1) ? ok : ov;
    int i = blockIdx.x * 256 + threadIdx.x;
    long e = (long)i * 4;
    int b = (int)(e >> 21);
    int d = (int)(e & 1023);
    float4 xv = reinterpret_cast<const float4*>(x)[i];
    float4 pv = *reinterpret_cast<const float4*>(pe + b * 1024 + d);
    ushort4 r;
    r.x = f2bf(xv.x + pv.x); r.y = f2bf(xv.y + pv.y);
    r.z = f2bf(xv.z + pv.z); r.w = f2bf(xv.w + pv.w);
    reinterpret_cast<ushort4*>(o)[i] = r;
}

// ------------------------------------------------------------------
// gemm8p: persistent QKV projection, 256 blocks x 512 thr, 2 assignments each.
// Assignment 1 (verified r14-16): full 256x256 8-phase tile of Q (blk<128) or K.
// Assignment 2 (NEW): half-tile 256x128 of V-proj with gemm8-style 2-phase/K-tile
//   counted-vmcnt schedule (wave grid 2x4, wave tile 128x32, acc[8][2]).
__global__ __launch_bounds__(512, 2) void gemm8p(const unsigned short* __restrict__ A0,
                                                 const unsigned short* __restrict__ W0,
                                                 const float* __restrict__ bq,
                                                 const float* __restrict__ bk,
                                                 const float* __restrict__ bv,
                                                 unsigned short* __restrict__ oq,
                                                 unsigned short* __restrict__ ok,
                                                 unsigned short* __restrict__ ov,
                                                 float qscale) {
    const int NT = 16;                        // K=1024 / BK=64
    __shared__ __align__(16) unsigned short lsA[2][256 * 64];
    __shared__ __align__(16) unsigned short lsB[2][256 * 64];

    int blk = blockIdx.x;
    int tid = threadIdx.x, wave = tid >> 6, lane = tid & 63;
    int lg = lane >> 4, l15 = lane & 15;
    int srow = tid >> 3;
    int scol = ((tid ^ srow) & 7) * 8;        // pre-swizzled source col (elems)
    int swz_ = (l15 & 7) << 4;

    // ================= Assignment 1: full 256^2 tile, z = blk>>7 =================
    {
        int z = blk >> 7;                     // 0 or 1
        int rem = blk & 127;
        int brow = (rem >> 2) * 256;
        int bcol = (rem & 3) * 256;
        const unsigned short* A = A0 + (size_t)z * 8192 * 1024;
        const unsigned short* W = W0 + (size_t)z * 1024 * 1024;
        const float* bias = (z == 0) ? bq : bk;
        float scale = (z == 0) ? qscale : 1.0f;
        unsigned short* out = (z == 0) ? oq : ok;

        int wr = wave >> 2, wc = wave & 3;    // 2 x 4 wave grid
        const unsigned short* pA = A + (long)(brow + srow) * 1024 + scol;
        const unsigned short* pB = W + (long)(bcol + srow) * 1024 + scol;

        f32x4 acc[8][4];
#pragma unroll
        for (int m = 0; m < 8; ++m)
#pragma unroll
            for (int n = 0; n < 4; ++n) acc[m][n] = f32x4{0.f, 0.f, 0.f, 0.f};

#define SA(t, bi, q) gll16(pA + (t) * 64 + (q) * 65536,                     \
                           (char*)lsA[bi] + ((q) * 512 + wave * 64) * 16)
#define SB(t, bi, q) gll16(pB + (t) * 64 + (q) * 65536,                     \
                           (char*)lsB[bi] + ((q) * 512 + wave * 64) * 16)

        SB(0, 0, 0); SB(0, 0, 1); SB(0, 0, 2); SB(0, 0, 3);
        SA(0, 0, 0); SA(0, 0, 2); SA(0, 0, 1); SA(0, 0, 3);
        asm volatile("s_waitcnt vmcnt(2)" ::: "memory");
        __builtin_amdgcn_s_barrier();

        for (int t = 0; t < NT; ++t) {
            int cb = t & 1, nb = cb ^ 1;
            const char* KA = (const char*)lsA[cb];
            const char* KB = (const char*)lsB[cb];
            short8 af0[4][2], af1[4][2], bf0[2][2], bf1[2][2];
            const bool st = (t < NT - 1);

            // q1: (m0-3, n0-1)
#pragma unroll
            for (int m = 0; m < 4; ++m)
#pragma unroll
                for (int kk = 0; kk < 2; ++kk)
                    af0[m][kk] = *(const short8*)(KA + (wr * 128 + m * 16 + l15) * 128 +
                                                  (((kk * 4 + lg) << 4) ^ swz_));
#pragma unroll
            for (int n = 0; n < 2; ++n)
#pragma unroll
                for (int kk = 0; kk < 2; ++kk)
                    bf0[n][kk] = *(const short8*)(KB + (wc * 64 + n * 16 + l15) * 128 +
                                                  (((kk * 4 + lg) << 4) ^ swz_));
            if (st) { SB(t + 1, nb, 0); SB(t + 1, nb, 1); }
            __builtin_amdgcn_s_barrier();
            asm volatile("s_waitcnt lgkmcnt(0)" ::: "memory");
            __builtin_amdgcn_s_setprio(1);
#pragma unroll
            for (int m = 0; m < 4; ++m)
#pragma unroll
                for (int n = 0; n < 2; ++n)
#pragma unroll
                    for (int kk = 0; kk < 2; ++kk)
                        acc[m][n] = MFMA16(af0[m][kk], bf0[n][kk], acc[m][n]);
            __builtin_amdgcn_s_setprio(0);
            __builtin_amdgcn_s_barrier();

            // q2: (m0-3, n2-3)
#pragma unroll
            for (int n = 0; n < 2; ++n)
#pragma unroll
                for (int kk = 0; kk < 2; ++kk)
                    bf1[n][kk] = *(const short8*)(KB + (wc * 64 + (n + 2) * 16 + l15) * 128 +
                                                  (((kk * 4 + lg) << 4) ^ swz_));
            if (st) { SB(t + 1, nb, 2); SB(t + 1, nb, 3); }
            if (st) { asm volatile("s_waitcnt vmcnt(4)" ::: "memory"); }
            else    { asm volatile("s_waitcnt vmcnt(0)" ::: "memory"); }
            __builtin_amdgcn_s_barrier();
            asm volatile("s_waitcnt lgkmcnt(0)" ::: "memory");
            __builtin_amdgcn_s_setprio(1);
#pragma unroll
            for (int m = 0; m < 4; ++m)
#pragma unroll
                for (int n = 0; n < 2; ++n)
#pragma unroll
                    for (int kk = 0; kk < 2; ++kk)
                        acc[m][n + 2] = MFMA16(af0[m][kk], bf1[n][kk], acc[m][n + 2]);
            __builtin_amdgcn_s_setprio(0);
            __builtin_amdgcn_s_barrier();

            // q3: (m4-7, n0-1)
#pragma unroll
            for (int m = 0; m < 4; ++m)
#pragma unroll
                for (int kk = 0; kk < 2; ++kk)
                    af1[m][kk] = *(const short8*)(KA + (wr * 128 + (m + 4) * 16 + l15) * 128 +
                                                  (((kk * 4 + lg) << 4) ^ swz_));
            if (st) { SA(t + 1, nb, 0); SA(t + 1, nb, 2); }
            __builtin_amdgcn_s_barrier();
            asm volatile("s_waitcnt lgkmcnt(0)" ::: "memory");
            __builtin_amdgcn_s_setprio(1);
#pragma unroll
            for (int m = 0; m < 4; ++m)
#pragma unroll
                for (int n = 0; n < 2; ++n)
#pragma unroll
                    for (int kk = 0; kk < 2; ++kk)
                        acc[m + 4][n] = MFMA16(af1[m][kk], bf0[n][kk], acc[m + 4][n]);
            __builtin_amdgcn_s_setprio(0);
            __builtin_amdgcn_s_barrier();

            // q4: (m4-7, n2-3)
            if (st) {
                SA(t + 1, nb, 1); SA(t + 1, nb, 3);
                asm volatile("s_waitcnt vmcnt(2)" ::: "memory");
            }
            __builtin_amdgcn_s_barrier();
            __builtin_amdgcn_s_setprio(1);
#pragma unroll
            for (int m = 0; m < 4; ++m)
#pragma unroll
                for (int n = 0; n < 2; ++n)
#pragma unroll
                    for (int kk = 0; kk < 2; ++kk)
                        acc[m + 4][n + 2] = MFMA16(af1[m][kk], bf1[n][kk], acc[m + 4][n + 2]);
            __builtin_amdgcn_s_setprio(0);
            __builtin_amdgcn_s_barrier();
        }
#undef SA
#undef SB

        // epilogue: head-split bf16
#pragma unroll
        for (int m = 0; m < 8; ++m)
#pragma unroll
            for (int n = 0; n < 4; ++n) {
                int col = bcol + wc * 64 + n * 16 + l15;
                float bv_ = bias[col];
                int row0 = brow + wr * 128 + m * 16 + lg * 4;
#pragma unroll
                for (int r = 0; r < 4; ++r) {
                    int row = row0 + r;
                    float v = (acc[m][n][r] + bv_) * scale;
                    int b = row >> 11, s = row & 2047, h = col >> 6, d = col & 63;
                    out[(((long)(b * 16 + h) * 2048 + s) * 64 + d)] = f2bf(v);
                }
            }
    }

    // ====== Assignment 2: half-tile 256x128 of V-proj, 2-phase counted-vmcnt ======
    {
        int ti = blk >> 1;                    // 0..127
        int brow = (ti >> 2) * 256;
        int bcol = (ti & 3) * 256 + (blk & 1) * 128;
        const unsigned short* A = A0 + (size_t)2 * 8192 * 1024;
        const unsigned short* W = W0 + (size_t)2 * 1024 * 1024;

        int wr = wave >> 2, wc = wave & 3;    // 2 x 4 wave grid, wave tile 128x32
        const unsigned short* pA = A + (long)(brow + srow) * 1024 + scol;
        const unsigned short* pB = W + (long)(bcol + srow) * 1024 + scol;

        f32x4 acc[8][2];
#pragma unroll
        for (int m = 0; m < 8; ++m)
#pragma unroll
            for (int n = 0; n < 2; ++n) acc[m][n] = f32x4{0.f, 0.f, 0.f, 0.f};

#define SA2(t, bi, q) gll16(pA + (t) * 64 + (q) * 65536,                     \
                            (char*)lsA[bi] + ((q) * 512 + wave * 64) * 16)
#define SB2(t, bi, q) gll16(pB + (t) * 64 + (q) * 65536,                     \
                            (char*)lsB[bi] + ((q) * 512 + wave * 64) * 16)

        // prologue: B0,B1,A0,A2 then A1,A3 (6 units); leave A1,A3 in flight
        SB2(0, 0, 0); SB2(0, 0, 1); SA2(0, 0, 0); SA2(0, 0, 2);
        SA2(0, 0, 1); SA2(0, 0, 3);
        asm volatile("s_waitcnt vmcnt(2)" ::: "memory");
        __builtin_amdgcn_s_barrier();

        for (int t = 0; t < NT; ++t) {
            int cb = t & 1, nb = cb ^ 1;
            const char* KA = (const char*)lsA[cb];
            const char* KB = (const char*)lsB[cb];
            const bool st = (t < NT - 1);
            short8 af[8][2], bf[2][2];

            // ---- p1: (m0-3, n0-1); needs B0,B1,A0,A2(t) [guaranteed] ----
#pragma unroll
            for (int m = 0; m < 4; ++m)
#pragma unroll
                for (int kk = 0; kk < 2; ++kk)
                    af[m][kk] = *(const short8*)(KA + (wr * 128 + m * 16 + l15) * 128 +
                                                 (((kk * 4 + lg) << 4) ^ swz_));
#pragma unroll
            for (int n = 0; n < 2; ++n)
#pragma unroll
                for (int kk = 0; kk < 2; ++kk)
                    bf[n][kk] = *(const short8*)(KB + (wc * 32 + n * 16 + l15) * 128 +
                                                 (((kk * 4 + lg) << 4) ^ swz_));
            if (st) { SB2(t + 1, nb, 0); SB2(t + 1, nb, 1); SA2(t + 1, nb, 0); SA2(t + 1, nb, 2); }
            __builtin_amdgcn_s_barrier();
            asm volatile("s_waitcnt lgkmcnt(0)" ::: "memory");
            __builtin_amdgcn_s_setprio(1);
#pragma unroll
            for (int m = 0; m < 4; ++m)
#pragma unroll
                for (int n = 0; n < 2; ++n)
#pragma unroll
                    for (int kk = 0; kk < 2; ++kk)
                        acc[m][n] = MFMA16(af[m][kk], bf[n][kk], acc[m][n]);
            __builtin_amdgcn_s_setprio(0);
            // complete t's A1,A3 before the barrier preceding p2's reads
            if (st) { asm volatile("s_waitcnt vmcnt(4)" ::: "memory"); }
            else    { asm volatile("s_waitcnt vmcnt(0)" ::: "memory"); }
            __builtin_amdgcn_s_barrier();

            // ---- p2: (m4-7, n0-1); needs A1,A3(t) [guaranteed above] ----
#pragma unroll
            for (int m = 4; m < 8; ++m)
#pragma unroll
                for (int kk = 0; kk < 2; ++kk)
                    af[m][kk] = *(const short8*)(KA + (wr * 128 + m * 16 + l15) * 128 +
                                                 (((kk * 4 + lg) << 4) ^ swz_));
            if (st) { SA2(t + 1, nb, 1); SA2(t + 1, nb, 3); }
            __builtin_amdgcn_s_barrier();
            asm volatile("s_waitcnt lgkmcnt(0)" ::: "memory");
            __builtin_amdgcn_s_setprio(1);
#pragma unroll
            for (int m = 4; m < 8; ++m)
#pragma unroll
                for (int n = 0; n < 2; ++n)
#pragma unroll
                    for (int kk = 0; kk < 2; ++kk)
                        acc[m][n] = MFMA16(af[m][kk], bf[n][kk], acc[m][n]);
            __builtin_amdgcn_s_setprio(0);
            // complete t+1's B0,B1,A0,A2 before next p1's reads
            if (st) { asm volatile("s_waitcnt vmcnt(2)" ::: "memory"); }
            __builtin_amdgcn_s_barrier();
        }
#undef SA2
#undef SB2

        // epilogue: V^T [B][1024col][2048s], ushort4 pack (4 consecutive s)
#pragma unroll
        for (int m = 0; m < 8; ++m)
#pragma unroll
            for (int n = 0; n < 2; ++n) {
                int col = bcol + wc * 32 + n * 16 + l15;
                float bv_ = bv[col];
                int row0 = brow + wr * 128 + m * 16 + lg * 4;
                int b = row0 >> 11, s0 = row0 & 2047;
                ushort4 pk;
                pk.x = f2bf(acc[m][n][0] + bv_);
                pk.y = f2bf(acc[m][n][1] + bv_);
                pk.z = f2bf(acc[m][n][2] + bv_);
                pk.w = f2bf(acc[m][n][3] + bv_);
                *(ushort4*)(ov + ((long)(b * 1024 + col)) * 2048 + s0) = pk;
            }
    }
}

// ------------------------------------------------------------------
// Dense GEMM: 2-phase 128x128, 3-buffer counted vmcnt, XCD-chunked (r13-proven).
__global__ __launch_bounds__(256, 3) void gemm_dense(const unsigned short* __restrict__ A,
                                                     const unsigned short* __restrict__ W,
                                                     const float* __restrict__ bias,
                                                     float* __restrict__ out) {
    const int NT = 32;                        // K=1024 / BK=32
    __shared__ unsigned short lsA[3][128 * 32];
    __shared__ unsigned short lsB[3][128 * 32];

    int flat = blockIdx.x;
    int xcd = flat & 7;
    int s = flat >> 3;
    int brow = (xcd * 8 + (s & 7)) * 128;
    int bcol = (s >> 3) * 128;

    int tid = threadIdx.x;
    int wave = tid >> 6, lane = tid & 63, lg = lane >> 4, l15 = lane & 15;
    int wr = wave >> 1, wc = wave & 1;

    int c0 = wave * 64 + lane, c1 = 256 + c0;
    const unsigned short* sA0 = A + (long)(brow + (c0 >> 2)) * 1024 + ((c0 ^ (c0 >> 2)) & 3) * 8;
    const unsigned short* sA1 = A + (long)(brow + (c1 >> 2)) * 1024 + ((c1 ^ (c1 >> 2)) & 3) * 8;
    const unsigned short* sB0 = W + (long)(bcol + (c0 >> 2)) * 1024 + ((c0 ^ (c0 >> 2)) & 3) * 8;
    const unsigned short* sB1 = W + (long)(bcol + (c1 >> 2)) * 1024 + ((c1 ^ (c1 >> 2)) & 3) * 8;

    int cread = (lg * 16) ^ ((l15 & 3) << 4);

    f32x4 acc[4][4];
#pragma unroll
    for (int m = 0; m < 4; ++m)
#pragma unroll
        for (int n = 0; n < 4; ++n) acc[m][n] = f32x4{0.f, 0.f, 0.f, 0.f};

#define STG(k0, bi) do {                                                  \
        gll16(sA0 + (k0), (char*)lsA[bi] + (wave * 64) * 16);             \
        gll16(sA1 + (k0), (char*)lsA[bi] + (256 + wave * 64) * 16);       \
        gll16(sB0 + (k0), (char*)lsB[bi] + (wave * 64) * 16);             \
        gll16(sB1 + (k0), (char*)lsB[bi] + (256 + wave * 64) * 16);       \
    } while (0)

    STG(0, 0);
    STG(32, 1);

    int bi = 0, sb = 2;
    for (int t = 0; t < NT; ++t) {
        if (t == NT - 1) { asm volatile("s_waitcnt vmcnt(0)" ::: "memory"); }
        else             { asm volatile("s_waitcnt vmcnt(4)" ::: "memory"); }
        __builtin_amdgcn_s_barrier();
        if (t < NT - 2) STG((t + 2) * 32, sb);

        const char* KA = (const char*)lsA[bi];
        const char* KB = (const char*)lsB[bi];
        short8 af[4], bf_[4];
#pragma unroll
        for (int m = 0; m < 4; ++m) {
            int row = wr * 64 + m * 16 + l15;
            af[m] = *(const short8*)(KA + row * 64 + cread);
        }
#pragma unroll
        for (int n = 0; n < 4; ++n) {
            int col = wc * 64 + n * 16 + l15;
            bf_[n] = *(const short8*)(KB + col * 64 + cread);
        }
        __builtin_amdgcn_s_setprio(1);
#pragma unroll
        for (int m = 0; m < 4; ++m)
#pragma unroll
            for (int n = 0; n < 4; ++n) acc[m][n] = MFMA16(af[m], bf_[n], acc[m][n]);
        __builtin_amdgcn_s_setprio(0);

        bi = (bi == 2) ? 0 : bi + 1;
        sb = (sb == 2) ? 0 : sb + 1;
    }
#undef STG

#pragma unroll
    for (int m = 0; m < 4; ++m)
#pragma unroll
        for (int n = 0; n < 4; ++n) {
            int col = bcol + wc * 64 + n * 16 + l15;
            float bv_ = bias[col];
#pragma unroll
            for (int r = 0; r < 4; ++r) {
                int row = brow + wr * 64 + m * 16 + lg * 4 + r;
                out[(long)row * 1024 + col] = acc[m][n][r] + bv_;
            }
        }
}

// ------------------------------------------------------------------
// Flash attention (round-10 version, unchanged).
__global__ __launch_bounds__(256, 2) void attn_kernel(const unsigned short* __restrict__ Qh,
                                                      const unsigned short* __restrict__ Kh,
                                                      const unsigned short* __restrict__ Vt,
                                                      unsigned short* __restrict__ Om) {
    const int S = 2048;
    const int NT = S / 64;
    int flat = blockIdx.x;
    int nf_ = (flat & 7) * 64 + (flat >> 3);
    int qt = nf_ & 7;
    int bh = nf_ >> 3;
    int b = bh >> 4, h = bh & 15;

    int tid = threadIdx.x, wave = tid >> 6, lane = tid & 63;
    int l31 = lane & 31, hi = lane >> 5;

    __shared__ __align__(16) unsigned short Kl[3][4096];
    __shared__ __align__(16) unsigned short Vtl[3][4096];

    const unsigned short* Qb = Qh + (long)bh * S * 64;
    const unsigned short* Kb = Kh + (long)bh * S * 64;
    const unsigned short* Vb = Vt + (long)bh * 64 * S;

    int colS = ((((tid & 7) * 16) ^ (((tid >> 3) & 7) << 4)) >> 1);
    const unsigned short* srcK = Kb + (tid >> 3) * 64 + colS;
    const unsigned short* srcV = Vb + (tid >> 3) * 2048 + colS;

    short8 aq[2][4];
    {
        const unsigned short* qrow = Qb + (long)(qt * 256 + wave * 64 + l31) * 64 + hi * 8;
#pragma unroll
        for (int qf = 0; qf < 2; ++qf)
#pragma unroll
            for (int s = 0; s < 4; ++s)
                aq[qf][s] = *(const short8*)(qrow + qf * 32 * 64 + s * 16);
    }

    f32x16 oacc[2][2], lacc[2], z16;
#pragma unroll
    for (int r = 0; r < 16; ++r) {
        oacc[0][0][r] = 0.f; oacc[0][1][r] = 0.f;
        oacc[1][0][r] = 0.f; oacc[1][1][r] = 0.f;
        lacc[0][r] = 0.f; lacc[1][r] = 0.f;
        z16[r] = 0.f;
    }

    const short8 ones8 = {0x3F80, 0x3F80, 0x3F80, 0x3F80, 0x3F80, 0x3F80, 0x3F80, 0x3F80};
    const unsigned SEL = 0x07060302u;

    int rb0 = l31 * 128;
    int swz = (l31 & 7) << 4;

#define STAGE(kt, bi) do {                                              \
        const unsigned short* sk = srcK + (kt) * 4096;                  \
        gll16(sk,         (char*)Kl[bi] + wave * 1024);                 \
        gll16(sk + 2048,  (char*)Kl[bi] + 4096 + wave * 1024);          \
        const unsigned short* sv = srcV + (kt) * 64;                    \
        gll16(sv,         (char*)Vtl[bi] + wave * 1024);                \
        gll16(sv + 65536, (char*)Vtl[bi] + 4096 + wave * 1024);         \
    } while (0)

    STAGE(0, 0);
    STAGE(1, 1);

    int bi = 0, sb = 2;
    for (int kt = 0; kt < NT; ++kt) {
        if (kt == NT - 1) { asm volatile("s_waitcnt vmcnt(0)" ::: "memory"); }
        else              { asm volatile("s_waitcnt vmcnt(4)" ::: "memory"); }
        __builtin_amdgcn_s_barrier();
        if (kt < NT - 2) STAGE(kt + 2, sb);

        const char* KlC = (const char*)Kl[bi];
        const char* VlC = (const char*)Vtl[bi];

        f32x16 sacc[2][2];
        __builtin_amdgcn_s_setprio(1);
#pragma unroll
        for (int blk = 0; blk < 2; ++blk) {
            short8 kf0 = *(const short8*)(KlC + blk * 4096 + rb0 + ((16 * hi) ^ swz));
            sacc[0][blk] = MFMA32(kf0, aq[0][0], z16);
            sacc[1][blk] = MFMA32(kf0, aq[1][0], z16);
#pragma unroll
            for (int s = 1; s < 4; ++s) {
                short8 kf = *(const short8*)(KlC + blk * 4096 + rb0 + ((32 * s + 16 * hi) ^ swz));
                sacc[0][blk] = MFMA32(kf, aq[0][s], sacc[0][blk]);
                sacc[1][blk] = MFMA32(kf, aq[1][s], sacc[1][blk]);
            }
        }
        __builtin_amdgcn_s_setprio(0);

#pragma unroll
        for (int qf = 0; qf < 2; ++qf)
#pragma unroll
            for (int blk = 0; blk < 2; ++blk)
#pragma unroll
                for (int r = 0; r < 16; ++r) sacc[qf][blk][r] = exp2_fast(sacc[qf][blk][r]);

#pragma unroll
        for (int s = 0; s < 4; ++s) {
            const int blk = s >> 1, base = (s & 1) * 8;
            short8 pa[2];
#pragma unroll
            for (int qf = 0; qf < 2; ++qf) {
                unsigned q0 = pk_perm(sacc[qf][blk][base + 0], sacc[qf][blk][base + 1], SEL);
                unsigned q1 = pk_perm(sacc[qf][blk][base + 2], sacc[qf][blk][base + 3], SEL);
                unsigned q2 = pk_perm(sacc[qf][blk][base + 4], sacc[qf][blk][base + 5], SEL);
                unsigned q3 = pk_perm(sacc[qf][blk][base + 6], sacc[qf][blk][base + 7], SEL);
                pl32_swap(q0, q2);
                pl32_swap(q1, q3);
                uint4v pw; pw[0] = q0; pw[1] = q1; pw[2] = q2; pw[3] = q3;
                pa[qf] = __builtin_bit_cast(short8, pw);
            }
            __builtin_amdgcn_s_setprio(1);
#pragma unroll
            for (int dblk = 0; dblk < 2; ++dblk) {
                short8 vf = *(const short8*)(VlC + dblk * 4096 + rb0 + ((32 * s + 16 * hi) ^ swz));
                oacc[0][dblk] = MFMA32(pa[0], vf, oacc[0][dblk]);
                oacc[1][dblk] = MFMA32(pa[1], vf, oacc[1][dblk]);
            }
            lacc[0] = MFMA32(pa[0], ones8, lacc[0]);
            lacc[1] = MFMA32(pa[1], ones8, lacc[1]);
            __builtin_amdgcn_s_setprio(0);
        }
        bi = (bi == 2) ? 0 : bi + 1;
        sb = (sb == 2) ? 0 : sb + 1;
    }
#undef STAGE

#pragma unroll
    for (int qf = 0; qf < 2; ++qf) {
        float inv[16];
#pragma unroll
        for (int r = 0; r < 16; ++r) inv[r] = 1.0f / lacc[qf][r];
        int qrow0 = qt * 256 + wave * 64 + qf * 32 + 4 * hi;
#pragma unroll
        for (int dblk = 0; dblk < 2; ++dblk)
#pragma unroll
            for (int r = 0; r < 16; ++r) {
                int qrow = qrow0 + (r & 3) + 8 * (r >> 2);
                int d = h * 64 + dblk * 32 + l31;
                float v = oacc[qf][dblk][r] * inv[r];
                Om[((long)b * 2048 + qrow) * 1024 + d] = f2bf(v);
            }
    }
}

// ------------------------------------------------------------------
extern "C" void kernel_launch(void* const* d_in, const int* in_sizes, int n_in,
                              void* d_out, int out_size, void* d_ws, size_t ws_size,
                              hipStream_t stream) {
    const float* v_in = (const float*)d_in[0];
    const float* k_in = (const float*)d_in[1];
    const float* q_in = (const float*)d_in[2];
    const float* wq_w = (const float*)d_in[3];
    const float* wq_b = (const float*)d_in[4];
    const float* wk_w = (const float*)d_in[5];
    const float* wk_b = (const float*)d_in[6];
    const float* wv_w = (const float*)d_in[7];
    const float* wv_b = (const float*)d_in[8];
    const float* wd_w = (const float*)d_in[9];
    const float* wd_b = (const float*)d_in[10];
    const float* pe   = (const float*)d_in[11];

    const long SZ = 8192L * 1024 * 2;
    char* ws = (char*)d_ws;
    unsigned short* xq = (unsigned short*)(ws + 0);          // xq,xk,xv contiguous
    unsigned short* xk = (unsigned short*)(ws + SZ);
    unsigned short* xv = (unsigned short*)(ws + 2 * SZ);
    unsigned short* qh = (unsigned short*)(ws + 3 * SZ);
    unsigned short* kh = (unsigned short*)(ws + 4 * SZ);
    unsigned short* vt = (unsigned short*)(ws + 5 * SZ);
    unsigned short* wqb16 = (unsigned short*)(ws + 6 * SZ);  // wq,wk,wv,wd contiguous

    pe_wcast<<<dim3(8192, 4), 256, 0, stream>>>(q_in, k_in, v_in, pe,
                                                wq_w, wk_w, wv_w, wd_w,
                                                xq, xk, xv, wqb16);

    const float QSCALE = 0.125f * 1.44269504088896f;   // fold 1/sqrt(64) * log2(e)
    gemm8p<<<256, 512, 0, stream>>>(
        xq, wqb16, wq_b, wk_b, wv_b, qh, kh, vt, QSCALE);

    unsigned short* om = xq;
    attn_kernel<<<512, 256, 0, stream>>>(qh, kh, vt, om);

    gemm_dense<<<512, 256, 0, stream>>>(
        om, wqb16 + 3L * 1024 * 1024, wd_b, (float*)d_out);
}